// Round 7
// baseline (188.179 us; speedup 1.0000x reference)
//
#include <hip/hip_runtime.h>

// ---------------- types / helpers ----------------
typedef float  f32x4   __attribute__((ext_vector_type(4)));
typedef float  f32x16  __attribute__((ext_vector_type(16)));
typedef __bf16 bf16x8  __attribute__((ext_vector_type(8)));
typedef __bf16 bf16x4  __attribute__((ext_vector_type(4)));
typedef __bf16 bf16x2  __attribute__((ext_vector_type(2)));
typedef short  short8v __attribute__((ext_vector_type(8)));
typedef unsigned uint4v __attribute__((ext_vector_type(4)));

__device__ __forceinline__ short f2bf(float f) {
  unsigned u = __float_as_uint(f);
  unsigned r = (u + 0x7FFFu + ((u >> 16) & 1u)) >> 16;  // RNE
  return (short)r;
}

__device__ __forceinline__ f32x4 mfma16(bf16x8 a, bf16x8 b, f32x4 c) {
  return __builtin_amdgcn_mfma_f32_16x16x32_bf16(a, b, c, 0, 0, 0);
}
__device__ __forceinline__ f32x16 mfma32(bf16x8 a, bf16x8 b, f32x16 c) {
  return __builtin_amdgcn_mfma_f32_32x32x16_bf16(a, b, c, 0, 0, 0);
}

// async global->LDS, 16B per lane. lds base must be wave-uniform; HW adds lane*16.
__device__ __forceinline__ void gload16(const void* g, void* l) {
  __builtin_amdgcn_global_load_lds(
      (const __attribute__((address_space(1))) unsigned int*)g,
      (__attribute__((address_space(3))) unsigned int*)l,
      16, 0, 0);
}

// Build PV A-fragment for k-slice pair from packed P dwords via one cross-half
// exchange. pk[i] holds P pairs k_local = 8*(i>>1) + 4*hi + 2*(i&1) + {0,1}.
__device__ __forceinline__ bf16x8 p_exchange(const unsigned* pk, int a, int hi) {
  unsigned y1 = hi ? pk[4 * a + 0] : pk[4 * a + 2];
  unsigned z1 = __shfl_xor(y1, 32);
  unsigned y2 = hi ? pk[4 * a + 1] : pk[4 * a + 3];
  unsigned z2 = __shfl_xor(y2, 32);
  unsigned w0 = hi ? z1 : pk[4 * a + 0];
  unsigned w1 = hi ? z2 : pk[4 * a + 1];
  unsigned w2 = hi ? pk[4 * a + 2] : z1;
  unsigned w3 = hi ? pk[4 * a + 3] : z2;
  uint4v q4 = {w0, w1, w2, w3};
  return __builtin_bit_cast(bf16x8, q4);
}

// ---------------- problem constants ----------------
// B=2, T1=T2=2048, D_MODEL=1024, N_HEAD=16, D_HEAD=64

// ---------------- conversion kernels ----------------
__global__ __launch_bounds__(256) void cvt_copy(const float* __restrict__ in,
                                                short* __restrict__ out, int n4) {
  int i = blockIdx.x * blockDim.x + threadIdx.x;
  int stride = gridDim.x * blockDim.x;
  for (; i < n4; i += stride) {
    float4 v = *(const float4*)&in[i * 4];
    short4 o;
    o.x = f2bf(v.x); o.y = f2bf(v.y); o.z = f2bf(v.z); o.w = f2bf(v.w);
    *(short4*)&out[i * 4] = o;
  }
}

// 4 weight matrices [1024][1024] f32 (row=k,col=n) -> bf16 [n][k], one launch.
__global__ __launch_bounds__(256) void cvt_transpose4(const float* __restrict__ W0,
                                                      const float* __restrict__ W1,
                                                      const float* __restrict__ W2,
                                                      const float* __restrict__ W3,
                                                      short* __restrict__ T0,
                                                      short* __restrict__ T1,
                                                      short* __restrict__ T2,
                                                      short* __restrict__ T3) {
  __shared__ short t_s[64][72];
  int z = blockIdx.z;
  const float* W = (z == 0) ? W0 : (z == 1) ? W1 : (z == 2) ? W2 : W3;
  short* Wt = (z == 0) ? T0 : (z == 1) ? T1 : (z == 2) ? T2 : T3;
  int k0 = blockIdx.y * 64, n0 = blockIdx.x * 64;
  int tid = threadIdx.x;
#pragma unroll
  for (int i = 0; i < 4; i++) {
    int idx = i * 256 + tid;
    int r = idx >> 4, cg = idx & 15;
    float4 v = *(const float4*)&W[(k0 + r) * 1024 + n0 + cg * 4];
    t_s[cg * 4 + 0][r] = f2bf(v.x);
    t_s[cg * 4 + 1][r] = f2bf(v.y);
    t_s[cg * 4 + 2][r] = f2bf(v.z);
    t_s[cg * 4 + 3][r] = f2bf(v.w);
  }
  __syncthreads();
#pragma unroll
  for (int i = 0; i < 2; i++) {
    int idx = i * 256 + tid;
    int r = idx >> 3, cg = idx & 7;
    short8v val = *(short8v*)&t_s[r][cg * 8];
    *(short8v*)&Wt[(n0 + r) * 1024 + k0 + cg * 8] = val;
  }
}

// ---------------- GEMM: C[4096][N] = A[4096][1024] @ Bt^T ----------------
// EPI 0: N=1024, bf16 scatter to [B,H,T,64]          (Q projection)
// EPI 2: N=1024, f32 out + b_out                      (final projection)
// EPI 3: N=2048, cols<1024 -> K [B,H,T,64]; cols>=1024 -> V^T [B,H,64,T]
template <int EPI>
__global__ __launch_bounds__(256, 4) void gemm_bf16(const short* __restrict__ A,
                                                    const short* __restrict__ Bt,
                                                    void* __restrict__ out,
                                                    void* __restrict__ out2,
                                                    const float* __restrict__ bout) {
  constexpr int KD = 1024;
  constexpr int NB = (EPI == 3) ? 32 : 16;  // N-tiles
  __shared__ short a_s[64][64];
  __shared__ short b_s[64][64];
  int tid = threadIdx.x, w = tid >> 6, lane = tid & 63;
  int g = lane >> 4, c16 = lane & 15;
  int hsw = c16 & 7;

  // XCD swizzle (bijective: grid % 8 == 0)
  int lin = blockIdx.x + NB * blockIdx.y;
  int wk = (lin & 7) * (NB * 8) + (lin >> 3);
  int c0 = (wk & (NB - 1)) * 64, r0 = (wk / NB) * 64;

  int wr = (w >> 1) * 32, wc = (w & 1) * 32;
  f32x4 acc[2][2] = {};

  for (int kt = 0; kt < KD / 64; ++kt) {
    int k0 = kt * 64;
    __syncthreads();
#pragma unroll
    for (int i = 0; i < 2; i++) {
      int cb = i * 256 + w * 64;
      int c = cb + lane;
      int row = c >> 3, kg = c & 7;
      int sw = (kg ^ (row & 7)) * 8;   // pre-swizzled source col
      gload16(A + (r0 + row) * KD + k0 + sw, (char*)a_s + cb * 16);
      gload16(Bt + (c0 + row) * KD + k0 + sw, (char*)b_s + cb * 16);
    }
    __syncthreads();
#pragma unroll
    for (int kk = 0; kk < 2; kk++) {
      bf16x8 af[2], bf[2];
      int sl0 = ((4 * kk + g) ^ hsw) * 8;
#pragma unroll
      for (int m = 0; m < 2; m++) af[m] = *(const bf16x8*)&a_s[wr + m * 16 + c16][sl0];
#pragma unroll
      for (int n = 0; n < 2; n++) bf[n] = *(const bf16x8*)&b_s[wc + n * 16 + c16][sl0];
#pragma unroll
      for (int m = 0; m < 2; m++)
#pragma unroll
        for (int n = 0; n < 2; n++) acc[m][n] = mfma16(af[m], bf[n], acc[m][n]);
    }
  }

#pragma unroll
  for (int m = 0; m < 2; m++)
#pragma unroll
    for (int n = 0; n < 2; n++)
#pragma unroll
      for (int r = 0; r < 4; r++) {
        int row = r0 + wr + m * 16 + g * 4 + r;  // C/D: row=(lane>>4)*4+reg
        int col = c0 + wc + n * 16 + c16;        //      col=lane&15
        float v = acc[m][n][r];
        int b = row >> 11, t = row & 2047;
        if (EPI == 2) {
          ((float*)out)[row * 1024 + col] = v + bout[col];
        } else if (EPI == 0) {
          int h = col >> 6, d = col & 63;
          ((short*)out)[(((b * 16 + h) * 2048) + t) * 64 + d] = f2bf(v);
        } else {  // EPI 3: merged K | V^T
          if (col < 1024) {
            int h = col >> 6, d = col & 63;
            ((short*)out)[(((b * 16 + h) * 2048) + t) * 64 + d] = f2bf(v);
          } else {
            int cv = col - 1024;
            int h = cv >> 6, d = cv & 63;
            ((short*)out2)[(((b * 16 + h) * 64) + d) * 2048 + t] = f2bf(v);
          }
        }
      }
}

// ---------------- flash attention v6 ----------------
// = v5 structure (4 waves x 32 q-rows, 32x32 MFMA, swapped QK, in-register P,
// subtile-at-a-time to stay under 128 VGPR) with the bias stream fixed:
//  - bias pre-converted to bf16 (halves bytes)
//  - qb-grouped XCD swizzle: an XCD hosts only 2 qb values across all (h,b),
//    so its bias slice (1MB bf16) is L2-resident; bias loads become L2 hits
//    instead of L3 misses on the critical path.
__global__ __launch_bounds__(256, 4) void flash_attn(const short* __restrict__ Qg,
                                                     const short* __restrict__ Kg,
                                                     const short* __restrict__ Vtg,
                                                     const short* __restrict__ biasb,
                                                     short* __restrict__ Og) {
  __shared__ short k_s[2][64][64];   // [buf][k][d]  16B-slot XOR-swizzled by row&7
  __shared__ short v_s[2][64][64];   // [buf][d][k]  16B-slot XOR-swizzled by row&7

  int tid = threadIdx.x, w = tid >> 6, lane = tid & 63;
  int hi = lane >> 5, ll = lane & 31;
  int l7 = ll & 7;

  // qb-grouped XCD swizzle: lin bits [2:0]->qi[2:0] (=XCD), [6:3]->h, [7]->b,
  // [8]->qi[3]. Blocks sharing qb land on one XCD -> bias slice L2-resident.
  int lin = blockIdx.x + 16 * (blockIdx.y + 16 * blockIdx.z);  // grid (16,16,2)
  int qi = (lin & 7) | (((lin >> 8) & 1) << 3);
  int h = (lin >> 3) & 15;
  int b = (lin >> 7) & 1;
  int qb = qi * 128;

  const short* Qh = Qg + (size_t)(b * 16 + h) * 2048 * 64;
  const short* Kh = Kg + (size_t)(b * 16 + h) * 2048 * 64;
  const short* Vh = Vtg + (size_t)(b * 16 + h) * 64 * 2048;

  const float C1 = 0.125f * 1.44269504f;                 // atten_scale * log2(e)
  const float C2 = exp2f(-(float)(h + 1)) * 1.44269504f; // head_scale * log2(e)

  int qrow = qb + w * 32 + ll;
  const short* bp = biasb + (size_t)qrow * 2048 + 4 * hi;

  // ---- prologue: stage tile 0 (4 gload16/thread), Q B-frags to registers ----
#pragma unroll
  for (int i = 0; i < 2; i++) {
    int cb = i * 256 + w * 64;
    int c = cb + lane;
    int row = c >> 3, t8 = c & 7, sw = (t8 ^ (row & 7)) * 8;
    gload16(Kh + row * 64 + sw, (char*)&k_s[0][0][0] + cb * 16);
    gload16(Vh + row * 2048 + sw, (char*)&v_s[0][0][0] + cb * 16);
  }
  bf16x8 qf[4];
#pragma unroll
  for (int dm = 0; dm < 4; dm++)
    qf[dm] = *(const bf16x8*)(Qh + (size_t)qrow * 64 + dm * 16 + hi * 8);
  asm volatile("" ::: "memory");  // pin prologue VMEM oldest in the queue

  float l_run = 0.f;
  f32x16 o_acc[2] = {};  // [dt]: col d = dt*32+ll, row q = (r&3)+8*(r>>2)+4*hi

  for (int kt = 0; kt < 32; ++kt) {
    int cur = kt & 1;
    // bias for subtile 0 (k_local 0..31), bf16, issued early
    bf16x4 bv0[4];
#pragma unroll
    for (int u = 0; u < 4; u++)
      bv0[u] = *(const bf16x4*)(bp + kt * 64 + u * 8);

    if (kt < 31) {
      const short* Ks = Kh + (size_t)(kt + 1) * 64 * 64;
      const short* Vs = Vh + (kt + 1) * 64;
#pragma unroll
      for (int i = 0; i < 2; i++) {
        int cb = i * 256 + w * 64;
        int c = cb + lane;
        int row = c >> 3, t8 = c & 7, sw = (t8 ^ (row & 7)) * 8;
        gload16(Ks + row * 64 + sw, (char*)&k_s[cur ^ 1][0][0] + cb * 16);
        gload16(Vs + row * 2048 + sw, (char*)&v_s[cur ^ 1][0][0] + cb * 16);
      }
    }
    // In-order vmcnt retirement: prev iter's consumed bias implies cur-stage
    // complete in steady state; at kt=0 this drains prologue stage+Q exactly.
    asm volatile("s_waitcnt vmcnt(8)" ::: "memory");
    __builtin_amdgcn_s_barrier();  // (a) cur buffer staged on all waves

    // ======== subtile 0 (k rows 0..31) ========
    f32x16 sacc = {};
    __builtin_amdgcn_s_setprio(1);
#pragma unroll
    for (int dm = 0; dm < 4; dm++) {
      const short* kr = &k_s[cur][ll][((2 * dm + hi) ^ l7) * 8];
      sacc = mfma32(*(const bf16x8*)kr, qf[dm], sacc);
    }
    __builtin_amdgcn_s_setprio(0);

    float lp = 0.f;
    unsigned pk[8];
#pragma unroll
    for (int i = 0; i < 8; i++) {
      float b0 = (float)bv0[i >> 1][2 * (i & 1)];
      float b1 = (float)bv0[i >> 1][2 * (i & 1) + 1];
      float p0 = exp2f(sacc[2 * i] * C1 + b0 * C2);
      float p1 = exp2f(sacc[2 * i + 1] * C1 + b1 * C2);
      lp += p0 + p1;
      bf16x2 pp = {(__bf16)p0, (__bf16)p1};
      pk[i] = __builtin_bit_cast(unsigned, pp);
    }
    l_run += lp;

    // bias for subtile 1 (sacc/bv0 dead -> low pressure window)
    bf16x4 bv1[4];
#pragma unroll
    for (int u = 0; u < 4; u++)
      bv1[u] = *(const bf16x4*)(bp + kt * 64 + 32 + u * 8);

    __builtin_amdgcn_s_setprio(1);
#pragma unroll
    for (int a = 0; a < 2; a++) {
      bf16x8 PA = p_exchange(pk, a, hi);
#pragma unroll
      for (int dt = 0; dt < 2; dt++) {  // V k-slice m=a -> slot 2a+hi
        const short* vr = &v_s[cur][dt * 32 + ll][((2 * a + hi) ^ l7) * 8];
        o_acc[dt] = mfma32(PA, *(const bf16x8*)vr, o_acc[dt]);
      }
    }
    __builtin_amdgcn_s_setprio(0);
    asm volatile("" ::: "memory");  // tile boundary: keep subtile-1 ops below

    // ======== subtile 1 (k rows 32..63) ========
    f32x16 sacc1 = {};
    __builtin_amdgcn_s_setprio(1);
#pragma unroll
    for (int dm = 0; dm < 4; dm++) {
      const short* kr = &k_s[cur][32 + ll][((2 * dm + hi) ^ l7) * 8];
      sacc1 = mfma32(*(const bf16x8*)kr, qf[dm], sacc1);
    }
    __builtin_amdgcn_s_setprio(0);

    float lp1 = 0.f;
#pragma unroll
    for (int i = 0; i < 8; i++) {
      float b0 = (float)bv1[i >> 1][2 * (i & 1)];
      float b1 = (float)bv1[i >> 1][2 * (i & 1) + 1];
      float p0 = exp2f(sacc1[2 * i] * C1 + b0 * C2);
      float p1 = exp2f(sacc1[2 * i + 1] * C1 + b1 * C2);
      lp1 += p0 + p1;
      bf16x2 pp = {(__bf16)p0, (__bf16)p1};
      pk[i] = __builtin_bit_cast(unsigned, pp);
    }
    l_run += lp1;

    __builtin_amdgcn_s_setprio(1);
#pragma unroll
    for (int a = 0; a < 2; a++) {
      bf16x8 PA = p_exchange(pk, a, hi);
#pragma unroll
      for (int dt = 0; dt < 2; dt++) {  // V k-slice m=2+a -> slot 4+2a+hi
        const short* vr = &v_s[cur][dt * 32 + ll][((4 + 2 * a + hi) ^ l7) * 8];
        o_acc[dt] = mfma32(PA, *(const bf16x8*)vr, o_acc[dt]);
      }
    }
    __builtin_amdgcn_s_setprio(0);
    __builtin_amdgcn_s_barrier();  // (b) all waves done reading cur
  }

  // ---- l: lane holds partial for q=ll over its k-subset; sum halves ----
  l_run += __shfl_xor(l_run, 32);
  float invl = 1.f / l_run;  // valid for q = ll on all lanes

  // ---- store O (bf16 [B,T1,H*64]) ----
#pragma unroll
  for (int r = 0; r < 16; r++) {
    int q = (r & 3) + 8 * (r >> 2) + 4 * hi;
    float iv = __shfl(invl, q);
    int tg = qb + w * 32 + q;
#pragma unroll
    for (int dt = 0; dt < 2; dt++) {
      Og[(size_t)(b * 2048 + tg) * 1024 + h * 64 + dt * 32 + ll] =
          f2bf(o_acc[dt][r] * iv);
    }
  }
}

// ---------------- launcher ----------------
extern "C" void kernel_launch(void* const* d_in, const int* in_sizes, int n_in,
                              void* d_out, int out_size, void* d_ws, size_t ws_size,
                              hipStream_t stream) {
  const float* x    = (const float*)d_in[0];
  const float* ctx  = (const float*)d_in[1];
  const float* bias = (const float*)d_in[2];
  const float* Wq   = (const float*)d_in[3];
  const float* Wk   = (const float*)d_in[4];
  const float* Wv   = (const float*)d_in[5];
  const float* Wo   = (const float*)d_in[6];
  const float* bo   = (const float*)d_in[7];
  float* out = (float*)d_out;

  char* ws = (char*)d_ws;
  short* x_bf = (short*)(ws + 0);          // 8 MB  (4096x1024 bf16); reused as bias_bf
  short* c_bf = (short*)(ws + 8388608);    // 8 MB
  short* wq_t = (short*)(ws + 16777216);   // 2 MB  [N][K]
  short* wk_t = (short*)(ws + 18874368);   // 2 MB  (contiguous with wv_t)
  short* wv_t = (short*)(ws + 20971520);   // 2 MB
  short* wo_t = (short*)(ws + 23068672);   // 2 MB
  short* q_ws = (short*)(ws + 25165824);   // 8 MB  [B,H,T1,64]
  short* k_ws = (short*)(ws + 33554432);   // 8 MB  [B,H,T2,64]
  short* v_ws = (short*)(ws + 41943040);   // 8 MB  [B,H,64,T2]
  short* o_ws = (short*)(ws + 50331648);   // 8 MB  [B,T1,1024]
  short* bias_bf = x_bf;                   // x_bf is dead after the Q-GEMM

  cvt_copy<<<1024, 256, 0, stream>>>(x, x_bf, 1048576);
  cvt_copy<<<1024, 256, 0, stream>>>(ctx, c_bf, 1048576);
  dim3 tg(16, 16, 4);
  cvt_transpose4<<<tg, 256, 0, stream>>>(Wq, Wk, Wv, Wo, wq_t, wk_t, wv_t, wo_t);

  dim3 gq(16, 64);  // N=1024
  gemm_bf16<0><<<gq, 256, 0, stream>>>(x_bf, wq_t, q_ws, nullptr, nullptr);
  dim3 gkv(32, 64); // N=2048 merged K|V
  gemm_bf16<3><<<gkv, 256, 0, stream>>>(c_bf, wk_t, k_ws, v_ws, nullptr);

  // bias f32 -> bf16 (into the x_bf region, free after the Q-GEMM)
  cvt_copy<<<1024, 256, 0, stream>>>(bias, bias_bf, 1048576);

  dim3 fg(16, 16, 2);
  flash_attn<<<fg, 256, 0, stream>>>(q_ws, k_ws, v_ws, bias_bf, o_ws);

  gemm_bf16<2><<<gq, 256, 0, stream>>>(o_ws, wo_t, out, nullptr, bo);
}

// Round 8
// 181.535 us; speedup vs baseline: 1.0366x; 1.0366x over previous
//
#include <hip/hip_runtime.h>

// ---------------- types / helpers ----------------
typedef float  f32x4   __attribute__((ext_vector_type(4)));
typedef float  f32x16  __attribute__((ext_vector_type(16)));
typedef __bf16 bf16x8  __attribute__((ext_vector_type(8)));
typedef __bf16 bf16x4  __attribute__((ext_vector_type(4)));
typedef __bf16 bf16x2  __attribute__((ext_vector_type(2)));
typedef short  short8v __attribute__((ext_vector_type(8)));
typedef unsigned uint4v __attribute__((ext_vector_type(4)));

__device__ __forceinline__ short f2bf(float f) {
  unsigned u = __float_as_uint(f);
  unsigned r = (u + 0x7FFFu + ((u >> 16) & 1u)) >> 16;  // RNE
  return (short)r;
}

__device__ __forceinline__ f32x4 mfma16(bf16x8 a, bf16x8 b, f32x4 c) {
  return __builtin_amdgcn_mfma_f32_16x16x32_bf16(a, b, c, 0, 0, 0);
}
__device__ __forceinline__ f32x16 mfma32(bf16x8 a, bf16x8 b, f32x16 c) {
  return __builtin_amdgcn_mfma_f32_32x32x16_bf16(a, b, c, 0, 0, 0);
}

// async global->LDS, 16B per lane. lds base must be wave-uniform; HW adds lane*16.
__device__ __forceinline__ void gload16(const void* g, void* l) {
  __builtin_amdgcn_global_load_lds(
      (const __attribute__((address_space(1))) unsigned int*)g,
      (__attribute__((address_space(3))) unsigned int*)l,
      16, 0, 0);
}

// Build PV A-fragment for k-slice pair from packed P dwords via one cross-half
// exchange. pk[i] holds P pairs k_local = 8*(i>>1) + 4*hi + 2*(i&1) + {0,1}.
__device__ __forceinline__ bf16x8 p_exchange(const unsigned* pk, int a, int hi) {
  unsigned y1 = hi ? pk[4 * a + 0] : pk[4 * a + 2];
  unsigned z1 = __shfl_xor(y1, 32);
  unsigned y2 = hi ? pk[4 * a + 1] : pk[4 * a + 3];
  unsigned z2 = __shfl_xor(y2, 32);
  unsigned w0 = hi ? z1 : pk[4 * a + 0];
  unsigned w1 = hi ? z2 : pk[4 * a + 1];
  unsigned w2 = hi ? pk[4 * a + 2] : z1;
  unsigned w3 = hi ? pk[4 * a + 3] : z2;
  uint4v q4 = {w0, w1, w2, w3};
  return __builtin_bit_cast(bf16x8, q4);
}

// ---------------- problem constants ----------------
// B=2, T1=T2=2048, D_MODEL=1024, N_HEAD=16, D_HEAD=64

// ---------------- conversion kernels ----------------
__global__ __launch_bounds__(256) void cvt_copy(const float* __restrict__ in,
                                                short* __restrict__ out, int n4) {
  int i = blockIdx.x * blockDim.x + threadIdx.x;
  int stride = gridDim.x * blockDim.x;
  for (; i < n4; i += stride) {
    float4 v = *(const float4*)&in[i * 4];
    short4 o;
    o.x = f2bf(v.x); o.y = f2bf(v.y); o.z = f2bf(v.z); o.w = f2bf(v.w);
    *(short4*)&out[i * 4] = o;
  }
}

// 4 weight matrices [1024][1024] f32 (row=k,col=n) -> bf16 [n][k], one launch.
__global__ __launch_bounds__(256) void cvt_transpose4(const float* __restrict__ W0,
                                                      const float* __restrict__ W1,
                                                      const float* __restrict__ W2,
                                                      const float* __restrict__ W3,
                                                      short* __restrict__ T0,
                                                      short* __restrict__ T1,
                                                      short* __restrict__ T2,
                                                      short* __restrict__ T3) {
  __shared__ short t_s[64][72];
  int z = blockIdx.z;
  const float* W = (z == 0) ? W0 : (z == 1) ? W1 : (z == 2) ? W2 : W3;
  short* Wt = (z == 0) ? T0 : (z == 1) ? T1 : (z == 2) ? T2 : T3;
  int k0 = blockIdx.y * 64, n0 = blockIdx.x * 64;
  int tid = threadIdx.x;
#pragma unroll
  for (int i = 0; i < 4; i++) {
    int idx = i * 256 + tid;
    int r = idx >> 4, cg = idx & 15;
    float4 v = *(const float4*)&W[(k0 + r) * 1024 + n0 + cg * 4];
    t_s[cg * 4 + 0][r] = f2bf(v.x);
    t_s[cg * 4 + 1][r] = f2bf(v.y);
    t_s[cg * 4 + 2][r] = f2bf(v.z);
    t_s[cg * 4 + 3][r] = f2bf(v.w);
  }
  __syncthreads();
#pragma unroll
  for (int i = 0; i < 2; i++) {
    int idx = i * 256 + tid;
    int r = idx >> 3, cg = idx & 7;
    short8v val = *(short8v*)&t_s[r][cg * 8];
    *(short8v*)&Wt[(n0 + r) * 1024 + k0 + cg * 8] = val;
  }
}

// ---------------- GEMM: C[4096][N] = A[4096][1024] @ Bt^T ----------------
// EPI 0: N=1024, bf16 scatter to [B,H,T,64]          (Q projection)
// EPI 2: N=1024, f32 out + b_out                      (final projection)
// EPI 3: N=2048, cols<1024 -> K [B,H,T,64]; cols>=1024 -> V^T [B,H,64,T]
template <int EPI>
__global__ __launch_bounds__(256, 4) void gemm_bf16(const short* __restrict__ A,
                                                    const short* __restrict__ Bt,
                                                    void* __restrict__ out,
                                                    void* __restrict__ out2,
                                                    const float* __restrict__ bout) {
  constexpr int KD = 1024;
  constexpr int NB = (EPI == 3) ? 32 : 16;  // N-tiles
  __shared__ short a_s[64][64];
  __shared__ short b_s[64][64];
  int tid = threadIdx.x, w = tid >> 6, lane = tid & 63;
  int g = lane >> 4, c16 = lane & 15;
  int hsw = c16 & 7;

  // XCD swizzle (bijective: grid % 8 == 0)
  int lin = blockIdx.x + NB * blockIdx.y;
  int wk = (lin & 7) * (NB * 8) + (lin >> 3);
  int c0 = (wk & (NB - 1)) * 64, r0 = (wk / NB) * 64;

  int wr = (w >> 1) * 32, wc = (w & 1) * 32;
  f32x4 acc[2][2] = {};

  for (int kt = 0; kt < KD / 64; ++kt) {
    int k0 = kt * 64;
    __syncthreads();
#pragma unroll
    for (int i = 0; i < 2; i++) {
      int cb = i * 256 + w * 64;
      int c = cb + lane;
      int row = c >> 3, kg = c & 7;
      int sw = (kg ^ (row & 7)) * 8;   // pre-swizzled source col
      gload16(A + (r0 + row) * KD + k0 + sw, (char*)a_s + cb * 16);
      gload16(Bt + (c0 + row) * KD + k0 + sw, (char*)b_s + cb * 16);
    }
    __syncthreads();
#pragma unroll
    for (int kk = 0; kk < 2; kk++) {
      bf16x8 af[2], bf[2];
      int sl0 = ((4 * kk + g) ^ hsw) * 8;
#pragma unroll
      for (int m = 0; m < 2; m++) af[m] = *(const bf16x8*)&a_s[wr + m * 16 + c16][sl0];
#pragma unroll
      for (int n = 0; n < 2; n++) bf[n] = *(const bf16x8*)&b_s[wc + n * 16 + c16][sl0];
#pragma unroll
      for (int m = 0; m < 2; m++)
#pragma unroll
        for (int n = 0; n < 2; n++) acc[m][n] = mfma16(af[m], bf[n], acc[m][n]);
    }
  }

#pragma unroll
  for (int m = 0; m < 2; m++)
#pragma unroll
    for (int n = 0; n < 2; n++)
#pragma unroll
      for (int r = 0; r < 4; r++) {
        int row = r0 + wr + m * 16 + g * 4 + r;  // C/D: row=(lane>>4)*4+reg
        int col = c0 + wc + n * 16 + c16;        //      col=lane&15
        float v = acc[m][n][r];
        int b = row >> 11, t = row & 2047;
        if (EPI == 2) {
          ((float*)out)[row * 1024 + col] = v + bout[col];
        } else if (EPI == 0) {
          int h = col >> 6, d = col & 63;
          ((short*)out)[(((b * 16 + h) * 2048) + t) * 64 + d] = f2bf(v);
        } else {  // EPI 3: merged K | V^T
          if (col < 1024) {
            int h = col >> 6, d = col & 63;
            ((short*)out)[(((b * 16 + h) * 2048) + t) * 64 + d] = f2bf(v);
          } else {
            int cv = col - 1024;
            int h = cv >> 6, d = cv & 63;
            ((short*)out2)[(((b * 16 + h) * 64) + d) * 2048 + t] = f2bf(v);
          }
        }
      }
}

// ---------------- flash attention v7 ----------------
// k-split groups for occupancy: 8 waves/block; waves 0-3 (gid=0) process even
// K-tiles, waves 4-7 (gid=1) odd K-tiles, same 128 q-rows. No-max softmax
// makes the merge exact: O = (O_e + O_o) / (l_e + l_o), combined via LDS at
// the epilogue. Per round the block stages TWO tiles (4 gload16/thread, same
// as v6 per-kt) and each wave computes one full 64-k tile.
// LDS 64KB -> 2 blocks/CU x 8 waves = 16 waves/CU = 4 waves/SIMD (vs 2 in v6).
// 32x32 MFMA, swapped QK, in-register P, bf16 bias, head-grouped XCD swizzle.
__global__ __launch_bounds__(512, 4) void flash_attn(const short* __restrict__ Qg,
                                                     const short* __restrict__ Kg,
                                                     const short* __restrict__ Vtg,
                                                     const short* __restrict__ biasb,
                                                     short* __restrict__ Og) {
  __shared__ short k_s[2][2][64][64];  // [buf][tile-parity][k][d], swizzled
  __shared__ short v_s[2][2][64][64];  // [buf][tile-parity][d][k], swizzled

  int tid = threadIdx.x, w = tid >> 6, lane = tid & 63;
  int gid = w >> 2, w4 = w & 3;
  int hi = lane >> 5, ll = lane & 31, l7 = ll & 7;

  // head-grouped XCD swizzle (r6): XCD hosts 4 heads x all qb -> K/V L2-fit
  int lin = blockIdx.x + 16 * (blockIdx.y + 16 * blockIdx.z);  // grid (16,16,2)
  int wk = (lin & 7) * 64 + (lin >> 3);
  int qb = (wk & 15) * 128;
  int h = (wk >> 4) & 15;
  int b = wk >> 8;

  const short* Qh = Qg + (size_t)(b * 16 + h) * 2048 * 64;
  const short* Kh = Kg + (size_t)(b * 16 + h) * 2048 * 64;
  const short* Vh = Vtg + (size_t)(b * 16 + h) * 64 * 2048;

  const float C1 = 0.125f * 1.44269504f;                 // atten_scale * log2(e)
  const float C2 = exp2f(-(float)(h + 1)) * 1.44269504f; // head_scale * log2(e)

  int qrow = qb + w4 * 32 + ll;
  const short* bp = biasb + (size_t)qrow * 2048 + 4 * hi;

  // ---- staging helper pattern: 4 chunks/thread cover K_A,V_A,K_B,V_B ----
  // chunk c = tid within 512: row = c>>3, t8 = c&7, swizzled src col.
  int srow = tid >> 3, st8 = tid & 7;
  int ssw = (st8 ^ (srow & 7)) * 8;

  // ---- prologue: stage tiles 0 (slot 0) and 1 (slot 1) into buf 0 ----
  {
    char* kd0 = (char*)&k_s[0][0][0][0] + w * 64 * 16;
    char* vd0 = (char*)&v_s[0][0][0][0] + w * 64 * 16;
    char* kd1 = (char*)&k_s[0][1][0][0] + w * 64 * 16;
    char* vd1 = (char*)&v_s[0][1][0][0] + w * 64 * 16;
    gload16(Kh + srow * 64 + ssw, kd0);
    gload16(Vh + srow * 2048 + ssw, vd0);
    gload16(Kh + 64 * 64 + srow * 64 + ssw, kd1);
    gload16(Vh + srow * 2048 + 64 + ssw, vd1);
  }
  bf16x8 qf[4];
#pragma unroll
  for (int dm = 0; dm < 4; dm++)
    qf[dm] = *(const bf16x8*)(Qh + (size_t)qrow * 64 + dm * 16 + hi * 8);
  asm volatile("" ::: "memory");  // pin prologue VMEM oldest in the queue

  float l_run = 0.f;
  f32x16 o_acc[2] = {};  // [dt]: col d = dt*32+ll, row q = (r&3)+8*(r>>2)+4*hi

  for (int r = 0; r < 16; ++r) {
    int cur = r & 1;
    int kt = 2 * r + gid;  // this wave's tile
    // bias for subtile 0 (k_local 0..31), bf16, issued early
    bf16x4 bv0[4];
#pragma unroll
    for (int u = 0; u < 4; u++)
      bv0[u] = *(const bf16x4*)(bp + kt * 64 + u * 8);

    if (r < 15) {
      int tA = 2 * r + 2;  // -> slot 0 of buf cur^1
      char* kdA = (char*)&k_s[cur ^ 1][0][0][0] + w * 64 * 16;
      char* vdA = (char*)&v_s[cur ^ 1][0][0][0] + w * 64 * 16;
      char* kdB = (char*)&k_s[cur ^ 1][1][0][0] + w * 64 * 16;
      char* vdB = (char*)&v_s[cur ^ 1][1][0][0] + w * 64 * 16;
      gload16(Kh + (size_t)tA * 4096 + srow * 64 + ssw, kdA);
      gload16(Vh + srow * 2048 + tA * 64 + ssw, vdA);
      gload16(Kh + (size_t)(tA + 1) * 4096 + srow * 64 + ssw, kdB);
      gload16(Vh + srow * 2048 + (tA + 1) * 64 + ssw, vdB);
      // outstanding: [cur stage 4 oldest][bv0 4][next stage 4] -> drain cur
      asm volatile("s_waitcnt vmcnt(8)" ::: "memory");
    } else {
      asm volatile("s_waitcnt vmcnt(4)" ::: "memory");  // [cur 4][bv0 4]
    }
    __builtin_amdgcn_s_barrier();  // (a) cur buffer staged on all waves

    // ======== subtile 0 (k rows 0..31 of my tile) ========
    f32x16 sacc = {};
    __builtin_amdgcn_s_setprio(1);
#pragma unroll
    for (int dm = 0; dm < 4; dm++) {
      const short* kr = &k_s[cur][gid][ll][((2 * dm + hi) ^ l7) * 8];
      sacc = mfma32(*(const bf16x8*)kr, qf[dm], sacc);
    }
    __builtin_amdgcn_s_setprio(0);

    float lp = 0.f;
    unsigned pk[8];
#pragma unroll
    for (int i = 0; i < 8; i++) {
      float b0 = (float)bv0[i >> 1][2 * (i & 1)];
      float b1 = (float)bv0[i >> 1][2 * (i & 1) + 1];
      float p0 = exp2f(sacc[2 * i] * C1 + b0 * C2);
      float p1 = exp2f(sacc[2 * i + 1] * C1 + b1 * C2);
      lp += p0 + p1;
      bf16x2 pp = {(__bf16)p0, (__bf16)p1};
      pk[i] = __builtin_bit_cast(unsigned, pp);
    }
    l_run += lp;

    // bias for subtile 1 (sacc/bv0 dead -> low pressure window)
    bf16x4 bv1[4];
#pragma unroll
    for (int u = 0; u < 4; u++)
      bv1[u] = *(const bf16x4*)(bp + kt * 64 + 32 + u * 8);

    __builtin_amdgcn_s_setprio(1);
#pragma unroll
    for (int a = 0; a < 2; a++) {
      bf16x8 PA = p_exchange(pk, a, hi);
#pragma unroll
      for (int dt = 0; dt < 2; dt++) {  // V k-slice m=a -> slot 2a+hi
        const short* vr = &v_s[cur][gid][dt * 32 + ll][((2 * a + hi) ^ l7) * 8];
        o_acc[dt] = mfma32(PA, *(const bf16x8*)vr, o_acc[dt]);
      }
    }
    __builtin_amdgcn_s_setprio(0);
    asm volatile("" ::: "memory");  // keep subtile-1 ops below

    // ======== subtile 1 (k rows 32..63 of my tile) ========
    f32x16 sacc1 = {};
    __builtin_amdgcn_s_setprio(1);
#pragma unroll
    for (int dm = 0; dm < 4; dm++) {
      const short* kr = &k_s[cur][gid][32 + ll][((2 * dm + hi) ^ l7) * 8];
      sacc1 = mfma32(*(const bf16x8*)kr, qf[dm], sacc1);
    }
    __builtin_amdgcn_s_setprio(0);

    float lp1 = 0.f;
#pragma unroll
    for (int i = 0; i < 8; i++) {
      float b0 = (float)bv1[i >> 1][2 * (i & 1)];
      float b1 = (float)bv1[i >> 1][2 * (i & 1) + 1];
      float p0 = exp2f(sacc1[2 * i] * C1 + b0 * C2);
      float p1 = exp2f(sacc1[2 * i + 1] * C1 + b1 * C2);
      lp1 += p0 + p1;
      bf16x2 pp = {(__bf16)p0, (__bf16)p1};
      pk[i] = __builtin_bit_cast(unsigned, pp);
    }
    l_run += lp1;

    __builtin_amdgcn_s_setprio(1);
#pragma unroll
    for (int a = 0; a < 2; a++) {
      bf16x8 PA = p_exchange(pk, a, hi);
#pragma unroll
      for (int dt = 0; dt < 2; dt++) {  // V k-slice m=2+a -> slot 4+2a+hi
        const short* vr = &v_s[cur][gid][dt * 32 + ll][((4 + 2 * a + hi) ^ l7) * 8];
        o_acc[dt] = mfma32(PA, *(const bf16x8*)vr, o_acc[dt]);
      }
    }
    __builtin_amdgcn_s_setprio(0);
    __builtin_amdgcn_s_barrier();  // (b) all waves done reading cur
  }

  // ---- merge the two k-groups: O = (O_e + O_o)/(l_e + l_o) ----
  l_run += __shfl_xor(l_run, 32);   // lane's l for q=ll over its 16 tiles
  float* ox = (float*)&k_s[0][0][0][0];  // [4][32][64] f32 = 32 KB (k_s dead)
  float* lx = (float*)&v_s[0][0][0][0];  // [4][32] f32
  if (gid == 1) {
#pragma unroll
    for (int k = 0; k < 32; k++)  // column layout: bank = lane -> conflict-free
      ox[(w4 * 32 + k) * 64 + lane] = o_acc[k >> 4][k & 15];
    if (lane < 32) lx[w4 * 32 + lane] = l_run;
  }
  __syncthreads();
  if (gid == 0) {
    float invl = 1.f / (l_run + lx[w4 * 32 + ll]);
#pragma unroll
    for (int k = 0; k < 32; k++)
      o_acc[k >> 4][k & 15] += ox[(w4 * 32 + k) * 64 + lane];

    // ---- store O (bf16 [B,T1,H*64]) ----
#pragma unroll
    for (int r = 0; r < 16; r++) {
      int q = (r & 3) + 8 * (r >> 2) + 4 * hi;
      float iv = __shfl(invl, q);
      int tg = qb + w4 * 32 + q;
#pragma unroll
      for (int dt = 0; dt < 2; dt++) {
        Og[(size_t)(b * 2048 + tg) * 1024 + h * 64 + dt * 32 + ll] =
            f2bf(o_acc[dt][r] * iv);
      }
    }
  }
}

// ---------------- launcher ----------------
extern "C" void kernel_launch(void* const* d_in, const int* in_sizes, int n_in,
                              void* d_out, int out_size, void* d_ws, size_t ws_size,
                              hipStream_t stream) {
  const float* x    = (const float*)d_in[0];
  const float* ctx  = (const float*)d_in[1];
  const float* bias = (const float*)d_in[2];
  const float* Wq   = (const float*)d_in[3];
  const float* Wk   = (const float*)d_in[4];
  const float* Wv   = (const float*)d_in[5];
  const float* Wo   = (const float*)d_in[6];
  const float* bo   = (const float*)d_in[7];
  float* out = (float*)d_out;

  char* ws = (char*)d_ws;
  short* x_bf = (short*)(ws + 0);          // 8 MB; reused as bias_bf after Q-GEMM
  short* c_bf = (short*)(ws + 8388608);    // 8 MB
  short* wq_t = (short*)(ws + 16777216);   // 2 MB  [N][K]
  short* wk_t = (short*)(ws + 18874368);   // 2 MB  (contiguous with wv_t)
  short* wv_t = (short*)(ws + 20971520);   // 2 MB
  short* wo_t = (short*)(ws + 23068672);   // 2 MB
  short* q_ws = (short*)(ws + 25165824);   // 8 MB  [B,H,T1,64]
  short* k_ws = (short*)(ws + 33554432);   // 8 MB  [B,H,T2,64]
  short* v_ws = (short*)(ws + 41943040);   // 8 MB  [B,H,64,T2]
  short* o_ws = (short*)(ws + 50331648);   // 8 MB  [B,T1,1024]
  short* bias_bf = x_bf;                   // x_bf dead after the Q-GEMM

  cvt_copy<<<1024, 256, 0, stream>>>(x, x_bf, 1048576);
  cvt_copy<<<1024, 256, 0, stream>>>(ctx, c_bf, 1048576);
  dim3 tg(16, 16, 4);
  cvt_transpose4<<<tg, 256, 0, stream>>>(Wq, Wk, Wv, Wo, wq_t, wk_t, wv_t, wo_t);

  dim3 gq(16, 64);  // N=1024
  gemm_bf16<0><<<gq, 256, 0, stream>>>(x_bf, wq_t, q_ws, nullptr, nullptr);
  dim3 gkv(32, 64); // N=2048 merged K|V
  gemm_bf16<3><<<gkv, 256, 0, stream>>>(c_bf, wk_t, k_ws, v_ws, nullptr);

  // bias f32 -> bf16 (into the x_bf region, free after the Q-GEMM)
  cvt_copy<<<1024, 256, 0, stream>>>(bias, bias_bf, 1048576);

  dim3 fg(16, 16, 2);
  flash_attn<<<fg, 512, 0, stream>>>(q_ws, k_ws, v_ws, bias_bf, o_ws);

  gemm_bf16<2><<<gq, 256, 0, stream>>>(o_ws, wo_t, out, nullptr, bo);
}

// Round 9
// 176.867 us; speedup vs baseline: 1.0640x; 1.0264x over previous
//
#include <hip/hip_runtime.h>

// ---------------- types / helpers ----------------
typedef float  f32x4   __attribute__((ext_vector_type(4)));
typedef float  f32x16  __attribute__((ext_vector_type(16)));
typedef __bf16 bf16x8  __attribute__((ext_vector_type(8)));
typedef __bf16 bf16x4  __attribute__((ext_vector_type(4)));
typedef __bf16 bf16x2  __attribute__((ext_vector_type(2)));
typedef short  short8v __attribute__((ext_vector_type(8)));
typedef unsigned uint4v __attribute__((ext_vector_type(4)));

__device__ __forceinline__ short f2bf(float f) {
  unsigned u = __float_as_uint(f);
  unsigned r = (u + 0x7FFFu + ((u >> 16) & 1u)) >> 16;  // RNE
  return (short)r;
}

// native v_exp_f32 (exp2) — the libm exp2f is a multi-instruction OCML routine
__device__ __forceinline__ float exp2_native(float x) {
#if __has_builtin(__builtin_amdgcn_exp2f)
  return __builtin_amdgcn_exp2f(x);
#else
  float r;
  asm("v_exp_f32 %0, %1" : "=v"(r) : "v"(x));
  return r;
#endif
}

__device__ __forceinline__ f32x4 mfma16(bf16x8 a, bf16x8 b, f32x4 c) {
  return __builtin_amdgcn_mfma_f32_16x16x32_bf16(a, b, c, 0, 0, 0);
}
__device__ __forceinline__ f32x16 mfma32(bf16x8 a, bf16x8 b, f32x16 c) {
  return __builtin_amdgcn_mfma_f32_32x32x16_bf16(a, b, c, 0, 0, 0);
}

// async global->LDS, 16B per lane. lds base must be wave-uniform; HW adds lane*16.
__device__ __forceinline__ void gload16(const void* g, void* l) {
  __builtin_amdgcn_global_load_lds(
      (const __attribute__((address_space(1))) unsigned int*)g,
      (__attribute__((address_space(3))) unsigned int*)l,
      16, 0, 0);
}

// Build PV A-fragment for k-slice pair from packed P dwords via one cross-half
// exchange. pk[i] holds P pairs k_local = 8*(i>>1) + 4*hi + 2*(i&1) + {0,1}.
__device__ __forceinline__ bf16x8 p_exchange(const unsigned* pk, int a, int hi) {
  unsigned y1 = hi ? pk[4 * a + 0] : pk[4 * a + 2];
  unsigned z1 = __shfl_xor(y1, 32);
  unsigned y2 = hi ? pk[4 * a + 1] : pk[4 * a + 3];
  unsigned z2 = __shfl_xor(y2, 32);
  unsigned w0 = hi ? z1 : pk[4 * a + 0];
  unsigned w1 = hi ? z2 : pk[4 * a + 1];
  unsigned w2 = hi ? pk[4 * a + 2] : z1;
  unsigned w3 = hi ? pk[4 * a + 3] : z2;
  uint4v q4 = {w0, w1, w2, w3};
  return __builtin_bit_cast(bf16x8, q4);
}

// ---------------- problem constants ----------------
// B=2, T1=T2=2048, D_MODEL=1024, N_HEAD=16, D_HEAD=64

// ---------------- conversion kernels ----------------
__global__ __launch_bounds__(256) void cvt_copy(const float* __restrict__ in,
                                                short* __restrict__ out, int n4) {
  int i = blockIdx.x * blockDim.x + threadIdx.x;
  int stride = gridDim.x * blockDim.x;
  for (; i < n4; i += stride) {
    float4 v = *(const float4*)&in[i * 4];
    short4 o;
    o.x = f2bf(v.x); o.y = f2bf(v.y); o.z = f2bf(v.z); o.w = f2bf(v.w);
    *(short4*)&out[i * 4] = o;
  }
}

// 4 weight matrices [1024][1024] f32 (row=k,col=n) -> bf16 [n][k], one launch.
__global__ __launch_bounds__(256) void cvt_transpose4(const float* __restrict__ W0,
                                                      const float* __restrict__ W1,
                                                      const float* __restrict__ W2,
                                                      const float* __restrict__ W3,
                                                      short* __restrict__ T0,
                                                      short* __restrict__ T1,
                                                      short* __restrict__ T2,
                                                      short* __restrict__ T3) {
  __shared__ short t_s[64][72];
  int z = blockIdx.z;
  const float* W = (z == 0) ? W0 : (z == 1) ? W1 : (z == 2) ? W2 : W3;
  short* Wt = (z == 0) ? T0 : (z == 1) ? T1 : (z == 2) ? T2 : T3;
  int k0 = blockIdx.y * 64, n0 = blockIdx.x * 64;
  int tid = threadIdx.x;
#pragma unroll
  for (int i = 0; i < 4; i++) {
    int idx = i * 256 + tid;
    int r = idx >> 4, cg = idx & 15;
    float4 v = *(const float4*)&W[(k0 + r) * 1024 + n0 + cg * 4];
    t_s[cg * 4 + 0][r] = f2bf(v.x);
    t_s[cg * 4 + 1][r] = f2bf(v.y);
    t_s[cg * 4 + 2][r] = f2bf(v.z);
    t_s[cg * 4 + 3][r] = f2bf(v.w);
  }
  __syncthreads();
#pragma unroll
  for (int i = 0; i < 2; i++) {
    int idx = i * 256 + tid;
    int r = idx >> 3, cg = idx & 7;
    short8v val = *(short8v*)&t_s[r][cg * 8];
    *(short8v*)&Wt[(n0 + r) * 1024 + k0 + cg * 8] = val;
  }
}

// ---------------- GEMM: C[4096][N] = A[4096][1024] @ Bt^T ----------------
// EPI 0: N=1024, bf16 scatter to [B,H,T,64]          (Q projection)
// EPI 2: N=1024, f32 out + b_out                      (final projection)
// EPI 3: N=2048, cols<1024 -> K [B,H,T,64]; cols>=1024 -> V^T [B,H,64,T]
template <int EPI>
__global__ __launch_bounds__(256, 4) void gemm_bf16(const short* __restrict__ A,
                                                    const short* __restrict__ Bt,
                                                    void* __restrict__ out,
                                                    void* __restrict__ out2,
                                                    const float* __restrict__ bout) {
  constexpr int KD = 1024;
  constexpr int NB = (EPI == 3) ? 32 : 16;  // N-tiles
  __shared__ short a_s[64][64];
  __shared__ short b_s[64][64];
  int tid = threadIdx.x, w = tid >> 6, lane = tid & 63;
  int g = lane >> 4, c16 = lane & 15;
  int hsw = c16 & 7;

  // XCD swizzle (bijective: grid % 8 == 0)
  int lin = blockIdx.x + NB * blockIdx.y;
  int wk = (lin & 7) * (NB * 8) + (lin >> 3);
  int c0 = (wk & (NB - 1)) * 64, r0 = (wk / NB) * 64;

  int wr = (w >> 1) * 32, wc = (w & 1) * 32;
  f32x4 acc[2][2] = {};

  for (int kt = 0; kt < KD / 64; ++kt) {
    int k0 = kt * 64;
    __syncthreads();
#pragma unroll
    for (int i = 0; i < 2; i++) {
      int cb = i * 256 + w * 64;
      int c = cb + lane;
      int row = c >> 3, kg = c & 7;
      int sw = (kg ^ (row & 7)) * 8;   // pre-swizzled source col
      gload16(A + (r0 + row) * KD + k0 + sw, (char*)a_s + cb * 16);
      gload16(Bt + (c0 + row) * KD + k0 + sw, (char*)b_s + cb * 16);
    }
    __syncthreads();
#pragma unroll
    for (int kk = 0; kk < 2; kk++) {
      bf16x8 af[2], bf[2];
      int sl0 = ((4 * kk + g) ^ hsw) * 8;
#pragma unroll
      for (int m = 0; m < 2; m++) af[m] = *(const bf16x8*)&a_s[wr + m * 16 + c16][sl0];
#pragma unroll
      for (int n = 0; n < 2; n++) bf[n] = *(const bf16x8*)&b_s[wc + n * 16 + c16][sl0];
#pragma unroll
      for (int m = 0; m < 2; m++)
#pragma unroll
        for (int n = 0; n < 2; n++) acc[m][n] = mfma16(af[m], bf[n], acc[m][n]);
    }
  }

#pragma unroll
  for (int m = 0; m < 2; m++)
#pragma unroll
    for (int n = 0; n < 2; n++)
#pragma unroll
      for (int r = 0; r < 4; r++) {
        int row = r0 + wr + m * 16 + g * 4 + r;  // C/D: row=(lane>>4)*4+reg
        int col = c0 + wc + n * 16 + c16;        //      col=lane&15
        float v = acc[m][n][r];
        int b = row >> 11, t = row & 2047;
        if (EPI == 2) {
          ((float*)out)[row * 1024 + col] = v + bout[col];
        } else if (EPI == 0) {
          int h = col >> 6, d = col & 63;
          ((short*)out)[(((b * 16 + h) * 2048) + t) * 64 + d] = f2bf(v);
        } else {  // EPI 3: merged K | V^T
          if (col < 1024) {
            int h = col >> 6, d = col & 63;
            ((short*)out)[(((b * 16 + h) * 2048) + t) * 64 + d] = f2bf(v);
          } else {
            int cv = col - 1024;
            int h = cv >> 6, d = cv & 63;
            ((short*)out2)[(((b * 16 + h) * 64) + d) * 2048 + t] = f2bf(v);
          }
        }
      }
}

// ---------------- flash attention v8 ----------------
// = v7 k-split structure (8 waves; gid 0/1 take even/odd K-tiles; exact merge
// O=(O_e+O_o)/(l_e+l_o)) with the softmax VALU wall removed:
//  - exp2f (libm OCML, ~15-20 VALU ops) -> native v_exp_f32 (1 trans op)
//  - bias double-buffered in registers: round r prefetches round r+1's 16
//    values, hiding the L2/L3 latency under a full round
//  - lp accumulated in 4 independent partials (fp adds not reassociable)
__global__ __launch_bounds__(512, 4) void flash_attn(const short* __restrict__ Qg,
                                                     const short* __restrict__ Kg,
                                                     const short* __restrict__ Vtg,
                                                     const short* __restrict__ biasb,
                                                     short* __restrict__ Og) {
  __shared__ short k_s[2][2][64][64];  // [buf][tile-parity][k][d], swizzled
  __shared__ short v_s[2][2][64][64];  // [buf][tile-parity][d][k], swizzled

  int tid = threadIdx.x, w = tid >> 6, lane = tid & 63;
  int gid = w >> 2, w4 = w & 3;
  int hi = lane >> 5, ll = lane & 31, l7 = ll & 7;

  // head-grouped XCD swizzle: XCD hosts 4 heads x all qb -> K/V L2-fit
  int lin = blockIdx.x + 16 * (blockIdx.y + 16 * blockIdx.z);  // grid (16,16,2)
  int wk = (lin & 7) * 64 + (lin >> 3);
  int qb = (wk & 15) * 128;
  int h = (wk >> 4) & 15;
  int b = wk >> 8;

  const short* Qh = Qg + (size_t)(b * 16 + h) * 2048 * 64;
  const short* Kh = Kg + (size_t)(b * 16 + h) * 2048 * 64;
  const short* Vh = Vtg + (size_t)(b * 16 + h) * 64 * 2048;

  const float C1 = 0.125f * 1.44269504f;                 // atten_scale * log2(e)
  const float C2 = exp2f(-(float)(h + 1)) * 1.44269504f; // head_scale * log2(e)

  int qrow = qb + w4 * 32 + ll;
  const short* bp = biasb + (size_t)qrow * 2048 + 4 * hi;

  // staging pattern: chunk c = tid: row = c>>3, swizzled col
  int srow = tid >> 3, st8 = tid & 7;
  int ssw = (st8 ^ (srow & 7)) * 8;

  // ---- prologue: stage tiles 0,1 into buf 0; bias for round 0; Q frags ----
  {
    gload16(Kh + srow * 64 + ssw, (char*)&k_s[0][0][0][0] + w * 64 * 16);
    gload16(Vh + srow * 2048 + ssw, (char*)&v_s[0][0][0][0] + w * 64 * 16);
    gload16(Kh + 64 * 64 + srow * 64 + ssw, (char*)&k_s[0][1][0][0] + w * 64 * 16);
    gload16(Vh + srow * 2048 + 64 + ssw, (char*)&v_s[0][1][0][0] + w * 64 * 16);
  }
  bf16x4 bvA0[4], bvA1[4];
#pragma unroll
  for (int u = 0; u < 4; u++) {
    bvA0[u] = *(const bf16x4*)(bp + gid * 64 + u * 8);
    bvA1[u] = *(const bf16x4*)(bp + gid * 64 + 32 + u * 8);
  }
  bf16x8 qf[4];
#pragma unroll
  for (int dm = 0; dm < 4; dm++)
    qf[dm] = *(const bf16x8*)(Qh + (size_t)qrow * 64 + dm * 16 + hi * 8);
  asm volatile("" ::: "memory");  // pin prologue VMEM issue order

  float l0 = 0.f, l1 = 0.f, l2 = 0.f, l3 = 0.f;
  f32x16 o_acc[2] = {};  // [dt]: col d = dt*32+ll, row q = (r&3)+8*(r>>2)+4*hi

  for (int r = 0; r < 16; ++r) {
    int cur = r & 1;
    int kt = 2 * r + gid;  // this wave's tile

    // prefetch next round's bias + stage next tile pair
    bf16x4 bvB0[4], bvB1[4];
    if (r < 15) {
      const short* bpn = bp + (kt + 2) * 64;
#pragma unroll
      for (int u = 0; u < 4; u++) {
        bvB0[u] = *(const bf16x4*)(bpn + u * 8);
        bvB1[u] = *(const bf16x4*)(bpn + 32 + u * 8);
      }
      int tA = 2 * r + 2;
      gload16(Kh + (size_t)tA * 4096 + srow * 64 + ssw,
              (char*)&k_s[cur ^ 1][0][0][0] + w * 64 * 16);
      gload16(Vh + srow * 2048 + tA * 64 + ssw,
              (char*)&v_s[cur ^ 1][0][0][0] + w * 64 * 16);
      gload16(Kh + (size_t)(tA + 1) * 4096 + srow * 64 + ssw,
              (char*)&k_s[cur ^ 1][1][0][0] + w * 64 * 16);
      gload16(Vh + srow * 2048 + (tA + 1) * 64 + ssw,
              (char*)&v_s[cur ^ 1][1][0][0] + w * 64 * 16);
      // outstanding (oldest->newest): [stage_cur 4][bias_next 8][stage_next 4]
      asm volatile("s_waitcnt vmcnt(12)" ::: "memory");
    } else {
      asm volatile("s_waitcnt vmcnt(0)" ::: "memory");
    }
    __builtin_amdgcn_s_barrier();  // (a) cur buffer staged on all waves

    // ======== subtile 0 (k rows 0..31 of my tile) ========
    f32x16 sacc = {};
    __builtin_amdgcn_s_setprio(1);
#pragma unroll
    for (int dm = 0; dm < 4; dm++) {
      const short* kr = &k_s[cur][gid][ll][((2 * dm + hi) ^ l7) * 8];
      sacc = mfma32(*(const bf16x8*)kr, qf[dm], sacc);
    }
    __builtin_amdgcn_s_setprio(0);

    unsigned pk[8];
#pragma unroll
    for (int i = 0; i < 8; i++) {
      float b0 = (float)bvA0[i >> 1][2 * (i & 1)];
      float b1 = (float)bvA0[i >> 1][2 * (i & 1) + 1];
      float p0 = exp2_native(sacc[2 * i] * C1 + b0 * C2);
      float p1 = exp2_native(sacc[2 * i + 1] * C1 + b1 * C2);
      l0 += p0; l1 += p1;
      bf16x2 pp = {(__bf16)p0, (__bf16)p1};
      pk[i] = __builtin_bit_cast(unsigned, pp);
    }

    __builtin_amdgcn_s_setprio(1);
#pragma unroll
    for (int a = 0; a < 2; a++) {
      bf16x8 PA = p_exchange(pk, a, hi);
#pragma unroll
      for (int dt = 0; dt < 2; dt++) {  // V k-slice m=a -> slot 2a+hi
        const short* vr = &v_s[cur][gid][dt * 32 + ll][((2 * a + hi) ^ l7) * 8];
        o_acc[dt] = mfma32(PA, *(const bf16x8*)vr, o_acc[dt]);
      }
    }
    __builtin_amdgcn_s_setprio(0);
    asm volatile("" ::: "memory");  // keep subtile-1 ops below

    // ======== subtile 1 (k rows 32..63 of my tile) ========
    f32x16 sacc1 = {};
    __builtin_amdgcn_s_setprio(1);
#pragma unroll
    for (int dm = 0; dm < 4; dm++) {
      const short* kr = &k_s[cur][gid][32 + ll][((2 * dm + hi) ^ l7) * 8];
      sacc1 = mfma32(*(const bf16x8*)kr, qf[dm], sacc1);
    }
    __builtin_amdgcn_s_setprio(0);

#pragma unroll
    for (int i = 0; i < 8; i++) {
      float b0 = (float)bvA1[i >> 1][2 * (i & 1)];
      float b1 = (float)bvA1[i >> 1][2 * (i & 1) + 1];
      float p0 = exp2_native(sacc1[2 * i] * C1 + b0 * C2);
      float p1 = exp2_native(sacc1[2 * i + 1] * C1 + b1 * C2);
      l2 += p0; l3 += p1;
      bf16x2 pp = {(__bf16)p0, (__bf16)p1};
      pk[i] = __builtin_bit_cast(unsigned, pp);
    }

    __builtin_amdgcn_s_setprio(1);
#pragma unroll
    for (int a = 0; a < 2; a++) {
      bf16x8 PA = p_exchange(pk, a, hi);
#pragma unroll
      for (int dt = 0; dt < 2; dt++) {  // V k-slice m=2+a -> slot 4+2a+hi
        const short* vr = &v_s[cur][gid][dt * 32 + ll][((4 + 2 * a + hi) ^ l7) * 8];
        o_acc[dt] = mfma32(PA, *(const bf16x8*)vr, o_acc[dt]);
      }
    }
    __builtin_amdgcn_s_setprio(0);
    __builtin_amdgcn_s_barrier();  // (b) all waves done reading cur

    // rotate bias double-buffer
#pragma unroll
    for (int u = 0; u < 4; u++) { bvA0[u] = bvB0[u]; bvA1[u] = bvB1[u]; }
  }

  float l_run = (l0 + l1) + (l2 + l3);

  // ---- merge the two k-groups: O = (O_e + O_o)/(l_e + l_o) ----
  l_run += __shfl_xor(l_run, 32);   // lane's l for q=ll over its 16 tiles
  float* ox = (float*)&k_s[0][0][0][0];  // [4][32][64] f32 = 32 KB (k_s dead)
  float* lx = (float*)&v_s[0][0][0][0];  // [4][32] f32
  if (gid == 1) {
#pragma unroll
    for (int k = 0; k < 32; k++)  // column layout: bank = lane -> conflict-free
      ox[(w4 * 32 + k) * 64 + lane] = o_acc[k >> 4][k & 15];
    if (lane < 32) lx[w4 * 32 + lane] = l_run;
  }
  __syncthreads();
  if (gid == 0) {
    float invl = 1.f / (l_run + lx[w4 * 32 + ll]);
#pragma unroll
    for (int k = 0; k < 32; k++)
      o_acc[k >> 4][k & 15] += ox[(w4 * 32 + k) * 64 + lane];

    // ---- store O (bf16 [B,T1,H*64]) ----
#pragma unroll
    for (int r = 0; r < 16; r++) {
      int q = (r & 3) + 8 * (r >> 2) + 4 * hi;
      float iv = __shfl(invl, q);
      int tg = qb + w4 * 32 + q;
#pragma unroll
      for (int dt = 0; dt < 2; dt++) {
        Og[(size_t)(b * 2048 + tg) * 1024 + h * 64 + dt * 32 + ll] =
            f2bf(o_acc[dt][r] * iv);
      }
    }
  }
}

// ---------------- launcher ----------------
extern "C" void kernel_launch(void* const* d_in, const int* in_sizes, int n_in,
                              void* d_out, int out_size, void* d_ws, size_t ws_size,
                              hipStream_t stream) {
  const float* x    = (const float*)d_in[0];
  const float* ctx  = (const float*)d_in[1];
  const float* bias = (const float*)d_in[2];
  const float* Wq   = (const float*)d_in[3];
  const float* Wk   = (const float*)d_in[4];
  const float* Wv   = (const float*)d_in[5];
  const float* Wo   = (const float*)d_in[6];
  const float* bo   = (const float*)d_in[7];
  float* out = (float*)d_out;

  char* ws = (char*)d_ws;
  short* x_bf = (short*)(ws + 0);          // 8 MB; reused as bias_bf after Q-GEMM
  short* c_bf = (short*)(ws + 8388608);    // 8 MB
  short* wq_t = (short*)(ws + 16777216);   // 2 MB  [N][K]
  short* wk_t = (short*)(ws + 18874368);   // 2 MB  (contiguous with wv_t)
  short* wv_t = (short*)(ws + 20971520);   // 2 MB
  short* wo_t = (short*)(ws + 23068672);   // 2 MB
  short* q_ws = (short*)(ws + 25165824);   // 8 MB  [B,H,T1,64]
  short* k_ws = (short*)(ws + 33554432);   // 8 MB  [B,H,T2,64]
  short* v_ws = (short*)(ws + 41943040);   // 8 MB  [B,H,64,T2]
  short* o_ws = (short*)(ws + 50331648);   // 8 MB  [B,T1,1024]
  short* bias_bf = x_bf;                   // x_bf dead after the Q-GEMM

  cvt_copy<<<1024, 256, 0, stream>>>(x, x_bf, 1048576);
  cvt_copy<<<1024, 256, 0, stream>>>(ctx, c_bf, 1048576);
  dim3 tg(16, 16, 4);
  cvt_transpose4<<<tg, 256, 0, stream>>>(Wq, Wk, Wv, Wo, wq_t, wk_t, wv_t, wo_t);

  dim3 gq(16, 64);  // N=1024
  gemm_bf16<0><<<gq, 256, 0, stream>>>(x_bf, wq_t, q_ws, nullptr, nullptr);
  dim3 gkv(32, 64); // N=2048 merged K|V
  gemm_bf16<3><<<gkv, 256, 0, stream>>>(c_bf, wk_t, k_ws, v_ws, nullptr);

  // bias f32 -> bf16 (into the x_bf region, free after the Q-GEMM)
  cvt_copy<<<1024, 256, 0, stream>>>(bias, bias_bf, 1048576);

  dim3 fg(16, 16, 2);
  flash_attn<<<fg, 512, 0, stream>>>(q_ws, k_ws, v_ws, bias_bf, o_ws);

  gemm_bf16<2><<<gq, 256, 0, stream>>>(o_ws, wo_t, out, nullptr, bo);
}

// Round 10
// 174.251 us; speedup vs baseline: 1.0799x; 1.0150x over previous
//
#include <hip/hip_runtime.h>

// ---------------- types / helpers ----------------
typedef float  f32x4   __attribute__((ext_vector_type(4)));
typedef float  f32x16  __attribute__((ext_vector_type(16)));
typedef __bf16 bf16x8  __attribute__((ext_vector_type(8)));
typedef __bf16 bf16x2  __attribute__((ext_vector_type(2)));
typedef short  short8v __attribute__((ext_vector_type(8)));
typedef unsigned uint4v __attribute__((ext_vector_type(4)));

__device__ __forceinline__ short f2bf(float f) {
  unsigned u = __float_as_uint(f);
  unsigned r = (u + 0x7FFFu + ((u >> 16) & 1u)) >> 16;  // RNE
  return (short)r;
}

// native v_exp_f32 (exp2) — libm exp2f is a multi-instruction OCML routine
__device__ __forceinline__ float exp2_native(float x) {
#if __has_builtin(__builtin_amdgcn_exp2f)
  return __builtin_amdgcn_exp2f(x);
#else
  float r;
  asm("v_exp_f32 %0, %1" : "=v"(r) : "v"(x));
  return r;
#endif
}

__device__ __forceinline__ f32x4 mfma16(bf16x8 a, bf16x8 b, f32x4 c) {
  return __builtin_amdgcn_mfma_f32_16x16x32_bf16(a, b, c, 0, 0, 0);
}
__device__ __forceinline__ f32x16 mfma32(bf16x8 a, bf16x8 b, f32x16 c) {
  return __builtin_amdgcn_mfma_f32_32x32x16_bf16(a, b, c, 0, 0, 0);
}

// async global->LDS, 16B per lane. lds base must be wave-uniform; HW adds lane*16.
__device__ __forceinline__ void gload16(const void* g, void* l) {
  __builtin_amdgcn_global_load_lds(
      (const __attribute__((address_space(1))) unsigned int*)g,
      (__attribute__((address_space(3))) unsigned int*)l,
      16, 0, 0);
}

// Build PV A-fragment for k-slice pair from packed P dwords via one cross-half
// exchange. pk[i] holds P pairs k_local = 8*(i>>1) + 4*hi + 2*(i&1) + {0,1}.
__device__ __forceinline__ bf16x8 p_exchange(const unsigned* pk, int a, int hi) {
  unsigned y1 = hi ? pk[4 * a + 0] : pk[4 * a + 2];
  unsigned z1 = __shfl_xor(y1, 32);
  unsigned y2 = hi ? pk[4 * a + 1] : pk[4 * a + 3];
  unsigned z2 = __shfl_xor(y2, 32);
  unsigned w0 = hi ? z1 : pk[4 * a + 0];
  unsigned w1 = hi ? z2 : pk[4 * a + 1];
  unsigned w2 = hi ? pk[4 * a + 2] : z1;
  unsigned w3 = hi ? pk[4 * a + 3] : z2;
  uint4v q4 = {w0, w1, w2, w3};
  return __builtin_bit_cast(bf16x8, q4);
}

// ---------------- problem constants ----------------
// B=2, T1=T2=2048, D_MODEL=1024, N_HEAD=16, D_HEAD=64

// ---------------- conversion kernels ----------------
__global__ __launch_bounds__(256) void cvt_copy(const float* __restrict__ in,
                                                short* __restrict__ out, int n4) {
  int i = blockIdx.x * blockDim.x + threadIdx.x;
  int stride = gridDim.x * blockDim.x;
  for (; i < n4; i += stride) {
    float4 v = *(const float4*)&in[i * 4];
    short4 o;
    o.x = f2bf(v.x); o.y = f2bf(v.y); o.z = f2bf(v.z); o.w = f2bf(v.w);
    *(short4*)&out[i * 4] = o;
  }
}

// bias f32 [2048][2048] -> bf16 fragment order frag[Qi][w4][kt][s][half][lane][8]
// so flash reads 4 x 16B fully-coalesced loads per wave-round.
// Mapping: qrow = Qi*128 + w4*32 + (lane&31); kc = kt*64 + s*32 + kc5 with
// kc5 = 4*(lane>>5) + (r&3) + 8*(r>>2), r = half*8 + idx.
__global__ __launch_bounds__(256) void cvt_bias_frag(const float* __restrict__ bias,
                                                     short* __restrict__ frag) {
  __shared__ short lb[2][2][64][8];  // [s][half][lane][idx] = 4KB
  int kt = blockIdx.x, w4 = blockIdx.y, Qi = blockIdx.z;
  int t = threadIdx.x;
  int row = t >> 3;                 // 0..31
  int c0 = (t & 7) * 8;             // 0..56
  const float* src = bias + (size_t)(Qi * 128 + w4 * 32 + row) * 2048 + kt * 64 + c0;
  float4 v0 = *(const float4*)(src + 0);
  float4 v1 = *(const float4*)(src + 4);
  float vv[8] = {v0.x, v0.y, v0.z, v0.w, v1.x, v1.y, v1.z, v1.w};
#pragma unroll
  for (int j = 0; j < 8; j++) {
    int kc64 = c0 + j;
    int s = kc64 >> 5, kc5 = kc64 & 31;
    int hi = (kc5 >> 2) & 1, a = kc5 & 3, bq = kc5 >> 3;
    int half = bq >> 1, idx = a + 4 * (bq & 1);
    lb[s][half][hi * 32 + row][idx] = f2bf(vv[j]);
  }
  __syncthreads();
  // linear copy-out: 256 threads x 16B = 4KB
  short8v val = ((const short8v*)&lb[0][0][0][0])[t];
  size_t base = ((size_t)((Qi * 4 + w4) * 32 + kt)) * 2048;  // shorts
  *(short8v*)&frag[base + t * 8] = val;
}

// 4 weight matrices [1024][1024] f32 (row=k,col=n) -> bf16 [n][k], one launch.
__global__ __launch_bounds__(256) void cvt_transpose4(const float* __restrict__ W0,
                                                      const float* __restrict__ W1,
                                                      const float* __restrict__ W2,
                                                      const float* __restrict__ W3,
                                                      short* __restrict__ T0,
                                                      short* __restrict__ T1,
                                                      short* __restrict__ T2,
                                                      short* __restrict__ T3) {
  __shared__ short t_s[64][72];
  int z = blockIdx.z;
  const float* W = (z == 0) ? W0 : (z == 1) ? W1 : (z == 2) ? W2 : W3;
  short* Wt = (z == 0) ? T0 : (z == 1) ? T1 : (z == 2) ? T2 : T3;
  int k0 = blockIdx.y * 64, n0 = blockIdx.x * 64;
  int tid = threadIdx.x;
#pragma unroll
  for (int i = 0; i < 4; i++) {
    int idx = i * 256 + tid;
    int r = idx >> 4, cg = idx & 15;
    float4 v = *(const float4*)&W[(k0 + r) * 1024 + n0 + cg * 4];
    t_s[cg * 4 + 0][r] = f2bf(v.x);
    t_s[cg * 4 + 1][r] = f2bf(v.y);
    t_s[cg * 4 + 2][r] = f2bf(v.z);
    t_s[cg * 4 + 3][r] = f2bf(v.w);
  }
  __syncthreads();
#pragma unroll
  for (int i = 0; i < 2; i++) {
    int idx = i * 256 + tid;
    int r = idx >> 3, cg = idx & 7;
    short8v val = *(short8v*)&t_s[r][cg * 8];
    *(short8v*)&Wt[(n0 + r) * 1024 + k0 + cg * 8] = val;
  }
}

// ---------------- GEMM: C[4096][N] = A[4096][1024] @ Bt^T ----------------
// EPI 0: N=1024, bf16 scatter to [B,H,T,64]          (Q projection)
// EPI 2: N=1024, f32 out + b_out                      (final projection)
// EPI 3: N=2048, cols<1024 -> K [B,H,T,64]; cols>=1024 -> V^T [B,H,64,T]
template <int EPI>
__global__ __launch_bounds__(256, 4) void gemm_bf16(const short* __restrict__ A,
                                                    const short* __restrict__ Bt,
                                                    void* __restrict__ out,
                                                    void* __restrict__ out2,
                                                    const float* __restrict__ bout) {
  constexpr int KD = 1024;
  constexpr int NB = (EPI == 3) ? 32 : 16;  // N-tiles
  __shared__ short a_s[64][64];
  __shared__ short b_s[64][64];
  int tid = threadIdx.x, w = tid >> 6, lane = tid & 63;
  int g = lane >> 4, c16 = lane & 15;
  int hsw = c16 & 7;

  // XCD swizzle (bijective: grid % 8 == 0)
  int lin = blockIdx.x + NB * blockIdx.y;
  int wk = (lin & 7) * (NB * 8) + (lin >> 3);
  int c0 = (wk & (NB - 1)) * 64, r0 = (wk / NB) * 64;

  int wr = (w >> 1) * 32, wc = (w & 1) * 32;
  f32x4 acc[2][2] = {};

  for (int kt = 0; kt < KD / 64; ++kt) {
    int k0 = kt * 64;
    __syncthreads();
#pragma unroll
    for (int i = 0; i < 2; i++) {
      int cb = i * 256 + w * 64;
      int c = cb + lane;
      int row = c >> 3, kg = c & 7;
      int sw = (kg ^ (row & 7)) * 8;   // pre-swizzled source col
      gload16(A + (r0 + row) * KD + k0 + sw, (char*)a_s + cb * 16);
      gload16(Bt + (c0 + row) * KD + k0 + sw, (char*)b_s + cb * 16);
    }
    __syncthreads();
#pragma unroll
    for (int kk = 0; kk < 2; kk++) {
      bf16x8 af[2], bf[2];
      int sl0 = ((4 * kk + g) ^ hsw) * 8;
#pragma unroll
      for (int m = 0; m < 2; m++) af[m] = *(const bf16x8*)&a_s[wr + m * 16 + c16][sl0];
#pragma unroll
      for (int n = 0; n < 2; n++) bf[n] = *(const bf16x8*)&b_s[wc + n * 16 + c16][sl0];
#pragma unroll
      for (int m = 0; m < 2; m++)
#pragma unroll
        for (int n = 0; n < 2; n++) acc[m][n] = mfma16(af[m], bf[n], acc[m][n]);
    }
  }

#pragma unroll
  for (int m = 0; m < 2; m++)
#pragma unroll
    for (int n = 0; n < 2; n++)
#pragma unroll
      for (int r = 0; r < 4; r++) {
        int row = r0 + wr + m * 16 + g * 4 + r;  // C/D: row=(lane>>4)*4+reg
        int col = c0 + wc + n * 16 + c16;        //      col=lane&15
        float v = acc[m][n][r];
        int b = row >> 11, t = row & 2047;
        if (EPI == 2) {
          ((float*)out)[row * 1024 + col] = v + bout[col];
        } else if (EPI == 0) {
          int h = col >> 6, d = col & 63;
          ((short*)out)[(((b * 16 + h) * 2048) + t) * 64 + d] = f2bf(v);
        } else {  // EPI 3: merged K | V^T
          if (col < 1024) {
            int h = col >> 6, d = col & 63;
            ((short*)out)[(((b * 16 + h) * 2048) + t) * 64 + d] = f2bf(v);
          } else {
            int cv = col - 1024;
            int h = cv >> 6, d = cv & 63;
            ((short*)out2)[(((b * 16 + h) * 64) + d) * 2048 + t] = f2bf(v);
          }
        }
      }
}

// ---------------- flash attention v9 ----------------
// = v8 k-split structure with the bias stream de-fragmented:
//  - bias pre-permuted to MFMA fragment order -> 4 x 16B coalesced loads per
//    wave-round (contiguous 1KB per load) instead of 8 row-scattered loads
//    touching ~32 cache lines each
//  - setprio removed (m190: lockstep schedule -> neutral/negative)
// Register double-buffer for bias kept; vmcnt(8) drains [stage_cur 4][bias_cur 4].
__global__ __launch_bounds__(512, 4) void flash_attn(const short* __restrict__ Qg,
                                                     const short* __restrict__ Kg,
                                                     const short* __restrict__ Vtg,
                                                     const short* __restrict__ bfrag,
                                                     short* __restrict__ Og) {
  __shared__ short k_s[2][2][64][64];  // [buf][tile-parity][k][d], swizzled
  __shared__ short v_s[2][2][64][64];  // [buf][tile-parity][d][k], swizzled

  int tid = threadIdx.x, w = tid >> 6, lane = tid & 63;
  int gid = w >> 2, w4 = w & 3;
  int hi = lane >> 5, ll = lane & 31, l7 = ll & 7;

  // head-grouped XCD swizzle: XCD hosts 4 heads x all qb -> K/V L2-fit
  int lin = blockIdx.x + 16 * (blockIdx.y + 16 * blockIdx.z);  // grid (16,16,2)
  int wk = (lin & 7) * 64 + (lin >> 3);
  int Qi = wk & 15;
  int qb = Qi * 128;
  int h = (wk >> 4) & 15;
  int b = wk >> 8;

  const short* Qh = Qg + (size_t)(b * 16 + h) * 2048 * 64;
  const short* Kh = Kg + (size_t)(b * 16 + h) * 2048 * 64;
  const short* Vh = Vtg + (size_t)(b * 16 + h) * 64 * 2048;

  const float C1 = 0.125f * 1.44269504f;                 // atten_scale * log2(e)
  const float C2 = exp2f(-(float)(h + 1)) * 1.44269504f; // head_scale * log2(e)

  int qrow = qb + w4 * 32 + ll;
  // per-wave bias fragment base: frag[Qi][w4][kt][s][half][lane][8]
  const short* bw = bfrag + ((size_t)(Qi * 4 + w4) * 32) * 2048 + lane * 8;

  // staging pattern: chunk c = tid: row = c>>3, swizzled col
  int srow = tid >> 3, st8 = tid & 7;
  int ssw = (st8 ^ (srow & 7)) * 8;

  // ---- prologue: stage tiles 0,1 into buf 0; bias round 0; Q frags ----
  {
    gload16(Kh + srow * 64 + ssw, (char*)&k_s[0][0][0][0] + w * 64 * 16);
    gload16(Vh + srow * 2048 + ssw, (char*)&v_s[0][0][0][0] + w * 64 * 16);
    gload16(Kh + 64 * 64 + srow * 64 + ssw, (char*)&k_s[0][1][0][0] + w * 64 * 16);
    gload16(Vh + srow * 2048 + 64 + ssw, (char*)&v_s[0][1][0][0] + w * 64 * 16);
  }
  bf16x8 bvA[4];  // [s*2+half] for this round's tile
#pragma unroll
  for (int j = 0; j < 4; j++)
    bvA[j] = *(const bf16x8*)(bw + (size_t)gid * 2048 + j * 512);
  bf16x8 qf[4];
#pragma unroll
  for (int dm = 0; dm < 4; dm++)
    qf[dm] = *(const bf16x8*)(Qh + (size_t)qrow * 64 + dm * 16 + hi * 8);
  asm volatile("" ::: "memory");  // pin prologue VMEM issue order

  float l0 = 0.f, l1 = 0.f, l2 = 0.f, l3 = 0.f;
  f32x16 o_acc[2] = {};  // [dt]: col d = dt*32+ll, row q = (r&3)+8*(r>>2)+4*hi

  for (int r = 0; r < 16; ++r) {
    int cur = r & 1;
    int kt = 2 * r + gid;  // this wave's tile

    // prefetch next round's bias fragment + stage next tile pair
    bf16x8 bvB[4];
    if (r < 15) {
#pragma unroll
      for (int j = 0; j < 4; j++)
        bvB[j] = *(const bf16x8*)(bw + (size_t)(kt + 2) * 2048 + j * 512);
      int tA = 2 * r + 2;
      gload16(Kh + (size_t)tA * 4096 + srow * 64 + ssw,
              (char*)&k_s[cur ^ 1][0][0][0] + w * 64 * 16);
      gload16(Vh + srow * 2048 + tA * 64 + ssw,
              (char*)&v_s[cur ^ 1][0][0][0] + w * 64 * 16);
      gload16(Kh + (size_t)(tA + 1) * 4096 + srow * 64 + ssw,
              (char*)&k_s[cur ^ 1][1][0][0] + w * 64 * 16);
      gload16(Vh + srow * 2048 + (tA + 1) * 64 + ssw,
              (char*)&v_s[cur ^ 1][1][0][0] + w * 64 * 16);
      // outstanding: [stage_cur 4][bias_cur 4][bias_next 4][stage_next 4]
      // -> vmcnt(8) drains stage_cur + bias_cur (consumed this round)
      asm volatile("s_waitcnt vmcnt(8)" ::: "memory");
    } else {
      asm volatile("s_waitcnt vmcnt(0)" ::: "memory");
    }
    __builtin_amdgcn_s_barrier();  // (a) cur buffer staged on all waves

    // ======== subtile 0 (k rows 0..31 of my tile) ========
    f32x16 sacc = {};
#pragma unroll
    for (int dm = 0; dm < 4; dm++) {
      const short* kr = &k_s[cur][gid][ll][((2 * dm + hi) ^ l7) * 8];
      sacc = mfma32(*(const bf16x8*)kr, qf[dm], sacc);
    }

    unsigned pk[8];
#pragma unroll
    for (int i = 0; i < 8; i++) {
      float b0 = (float)(i < 4 ? bvA[0][2 * i] : bvA[1][2 * i - 8]);
      float b1 = (float)(i < 4 ? bvA[0][2 * i + 1] : bvA[1][2 * i - 7]);
      float p0 = exp2_native(sacc[2 * i] * C1 + b0 * C2);
      float p1 = exp2_native(sacc[2 * i + 1] * C1 + b1 * C2);
      l0 += p0; l1 += p1;
      bf16x2 pp = {(__bf16)p0, (__bf16)p1};
      pk[i] = __builtin_bit_cast(unsigned, pp);
    }

#pragma unroll
    for (int a = 0; a < 2; a++) {
      bf16x8 PA = p_exchange(pk, a, hi);
#pragma unroll
      for (int dt = 0; dt < 2; dt++) {  // V k-slice m=a -> slot 2a+hi
        const short* vr = &v_s[cur][gid][dt * 32 + ll][((2 * a + hi) ^ l7) * 8];
        o_acc[dt] = mfma32(PA, *(const bf16x8*)vr, o_acc[dt]);
      }
    }
    asm volatile("" ::: "memory");  // keep subtile-1 ops below

    // ======== subtile 1 (k rows 32..63 of my tile) ========
    f32x16 sacc1 = {};
#pragma unroll
    for (int dm = 0; dm < 4; dm++) {
      const short* kr = &k_s[cur][gid][32 + ll][((2 * dm + hi) ^ l7) * 8];
      sacc1 = mfma32(*(const bf16x8*)kr, qf[dm], sacc1);
    }

#pragma unroll
    for (int i = 0; i < 8; i++) {
      float b0 = (float)(i < 4 ? bvA[2][2 * i] : bvA[3][2 * i - 8]);
      float b1 = (float)(i < 4 ? bvA[2][2 * i + 1] : bvA[3][2 * i - 7]);
      float p0 = exp2_native(sacc1[2 * i] * C1 + b0 * C2);
      float p1 = exp2_native(sacc1[2 * i + 1] * C1 + b1 * C2);
      l2 += p0; l3 += p1;
      bf16x2 pp = {(__bf16)p0, (__bf16)p1};
      pk[i] = __builtin_bit_cast(unsigned, pp);
    }

#pragma unroll
    for (int a = 0; a < 2; a++) {
      bf16x8 PA = p_exchange(pk, a, hi);
#pragma unroll
      for (int dt = 0; dt < 2; dt++) {  // V k-slice m=2+a -> slot 4+2a+hi
        const short* vr = &v_s[cur][gid][dt * 32 + ll][((4 + 2 * a + hi) ^ l7) * 8];
        o_acc[dt] = mfma32(PA, *(const bf16x8*)vr, o_acc[dt]);
      }
    }
    __builtin_amdgcn_s_barrier();  // (b) all waves done reading cur

    // rotate bias double-buffer
#pragma unroll
    for (int j = 0; j < 4; j++) bvA[j] = bvB[j];
  }

  float l_run = (l0 + l1) + (l2 + l3);

  // ---- merge the two k-groups: O = (O_e + O_o)/(l_e + l_o) ----
  l_run += __shfl_xor(l_run, 32);   // lane's l for q=ll over its 16 tiles
  float* ox = (float*)&k_s[0][0][0][0];  // [4][32][64] f32 = 32 KB (k_s dead)
  float* lx = (float*)&v_s[0][0][0][0];  // [4][32] f32
  if (gid == 1) {
#pragma unroll
    for (int k = 0; k < 32; k++)  // column layout: bank = lane -> conflict-free
      ox[(w4 * 32 + k) * 64 + lane] = o_acc[k >> 4][k & 15];
    if (lane < 32) lx[w4 * 32 + lane] = l_run;
  }
  __syncthreads();
  if (gid == 0) {
    float invl = 1.f / (l_run + lx[w4 * 32 + ll]);
#pragma unroll
    for (int k = 0; k < 32; k++)
      o_acc[k >> 4][k & 15] += ox[(w4 * 32 + k) * 64 + lane];

    // ---- store O (bf16 [B,T1,H*64]) ----
#pragma unroll
    for (int r = 0; r < 16; r++) {
      int q = (r & 3) + 8 * (r >> 2) + 4 * hi;
      float iv = __shfl(invl, q);
      int tg = qb + w4 * 32 + q;
#pragma unroll
      for (int dt = 0; dt < 2; dt++) {
        Og[(size_t)(b * 2048 + tg) * 1024 + h * 64 + dt * 32 + ll] =
            f2bf(o_acc[dt][r] * iv);
      }
    }
  }
}

// ---------------- launcher ----------------
extern "C" void kernel_launch(void* const* d_in, const int* in_sizes, int n_in,
                              void* d_out, int out_size, void* d_ws, size_t ws_size,
                              hipStream_t stream) {
  const float* x    = (const float*)d_in[0];
  const float* ctx  = (const float*)d_in[1];
  const float* bias = (const float*)d_in[2];
  const float* Wq   = (const float*)d_in[3];
  const float* Wk   = (const float*)d_in[4];
  const float* Wv   = (const float*)d_in[5];
  const float* Wo   = (const float*)d_in[6];
  const float* bo   = (const float*)d_in[7];
  float* out = (float*)d_out;

  char* ws = (char*)d_ws;
  short* x_bf = (short*)(ws + 0);          // 8 MB; reused as bias frag after Q-GEMM
  short* c_bf = (short*)(ws + 8388608);    // 8 MB
  short* wq_t = (short*)(ws + 16777216);   // 2 MB  [N][K]
  short* wk_t = (short*)(ws + 18874368);   // 2 MB  (contiguous with wv_t)
  short* wv_t = (short*)(ws + 20971520);   // 2 MB
  short* wo_t = (short*)(ws + 23068672);   // 2 MB
  short* q_ws = (short*)(ws + 25165824);   // 8 MB  [B,H,T1,64]
  short* k_ws = (short*)(ws + 33554432);   // 8 MB  [B,H,T2,64]
  short* v_ws = (short*)(ws + 41943040);   // 8 MB  [B,H,64,T2]
  short* o_ws = (short*)(ws + 50331648);   // 8 MB  [B,T1,1024]
  short* bias_fr = x_bf;                   // x_bf dead after the Q-GEMM

  cvt_copy<<<1024, 256, 0, stream>>>(x, x_bf, 1048576);
  cvt_copy<<<1024, 256, 0, stream>>>(ctx, c_bf, 1048576);
  dim3 tg(16, 16, 4);
  cvt_transpose4<<<tg, 256, 0, stream>>>(Wq, Wk, Wv, Wo, wq_t, wk_t, wv_t, wo_t);

  dim3 gq(16, 64);  // N=1024
  gemm_bf16<0><<<gq, 256, 0, stream>>>(x_bf, wq_t, q_ws, nullptr, nullptr);
  dim3 gkv(32, 64); // N=2048 merged K|V
  gemm_bf16<3><<<gkv, 256, 0, stream>>>(c_bf, wk_t, k_ws, v_ws, nullptr);

  // bias f32 -> bf16 fragment order (into x_bf region, free after Q-GEMM)
  dim3 bg(32, 4, 16);  // (kt, w4, Qi)
  cvt_bias_frag<<<bg, 256, 0, stream>>>(bias, bias_fr);

  dim3 fg(16, 16, 2);
  flash_attn<<<fg, 512, 0, stream>>>(q_ws, k_ws, v_ws, bias_fr, o_ws);

  gemm_bf16<2><<<gq, 256, 0, stream>>>(o_ws, wo_t, out, nullptr, bo);
}

// Round 11
// 166.487 us; speedup vs baseline: 1.1303x; 1.0466x over previous
//
#include <hip/hip_runtime.h>

// ---------------- types / helpers ----------------
typedef float  f32x4   __attribute__((ext_vector_type(4)));
typedef float  f32x16  __attribute__((ext_vector_type(16)));
typedef __bf16 bf16x8  __attribute__((ext_vector_type(8)));
typedef __bf16 bf16x2  __attribute__((ext_vector_type(2)));
typedef short  short8v __attribute__((ext_vector_type(8)));
typedef unsigned uint4v __attribute__((ext_vector_type(4)));

__device__ __forceinline__ short f2bf(float f) {
  unsigned u = __float_as_uint(f);
  unsigned r = (u + 0x7FFFu + ((u >> 16) & 1u)) >> 16;  // RNE
  return (short)r;
}

// native v_exp_f32 (exp2) — libm exp2f is a multi-instruction OCML routine
__device__ __forceinline__ float exp2_native(float x) {
#if __has_builtin(__builtin_amdgcn_exp2f)
  return __builtin_amdgcn_exp2f(x);
#else
  float r;
  asm("v_exp_f32 %0, %1" : "=v"(r) : "v"(x));
  return r;
#endif
}

__device__ __forceinline__ f32x4 mfma16(bf16x8 a, bf16x8 b, f32x4 c) {
  return __builtin_amdgcn_mfma_f32_16x16x32_bf16(a, b, c, 0, 0, 0);
}
__device__ __forceinline__ f32x16 mfma32(bf16x8 a, bf16x8 b, f32x16 c) {
  return __builtin_amdgcn_mfma_f32_32x32x16_bf16(a, b, c, 0, 0, 0);
}

// async global->LDS, 16B per lane. lds base must be wave-uniform; HW adds lane*16.
__device__ __forceinline__ void gload16(const void* g, void* l) {
  __builtin_amdgcn_global_load_lds(
      (const __attribute__((address_space(1))) unsigned int*)g,
      (__attribute__((address_space(3))) unsigned int*)l,
      16, 0, 0);
}

// Build PV A-fragment for k-slice pair from packed P dwords via one cross-half
// exchange. pk[i] holds P pairs k_local = 8*(i>>1) + 4*hi + 2*(i&1) + {0,1}.
__device__ __forceinline__ bf16x8 p_exchange(const unsigned* pk, int a, int hi) {
  unsigned y1 = hi ? pk[4 * a + 0] : pk[4 * a + 2];
  unsigned z1 = __shfl_xor(y1, 32);
  unsigned y2 = hi ? pk[4 * a + 1] : pk[4 * a + 3];
  unsigned z2 = __shfl_xor(y2, 32);
  unsigned w0 = hi ? z1 : pk[4 * a + 0];
  unsigned w1 = hi ? z2 : pk[4 * a + 1];
  unsigned w2 = hi ? pk[4 * a + 2] : z1;
  unsigned w3 = hi ? pk[4 * a + 3] : z2;
  uint4v q4 = {w0, w1, w2, w3};
  return __builtin_bit_cast(bf16x8, q4);
}

// ---------------- problem constants ----------------
// B=2, T1=T2=2048, D_MODEL=1024, N_HEAD=16, D_HEAD=64

// ---------------- conversion kernels ----------------
__global__ __launch_bounds__(256) void cvt_copy(const float* __restrict__ in,
                                                short* __restrict__ out, int n4) {
  int i = blockIdx.x * blockDim.x + threadIdx.x;
  int stride = gridDim.x * blockDim.x;
  for (; i < n4; i += stride) {
    float4 v = *(const float4*)&in[i * 4];
    short4 o;
    o.x = f2bf(v.x); o.y = f2bf(v.y); o.z = f2bf(v.z); o.w = f2bf(v.w);
    *(short4*)&out[i * 4] = o;
  }
}

// bias f32 [2048][2048] -> bf16 fragment order frag[Qi][w4][kt][s][half][lane][8]
__global__ __launch_bounds__(256) void cvt_bias_frag(const float* __restrict__ bias,
                                                     short* __restrict__ frag) {
  __shared__ short lb[2][2][64][8];  // [s][half][lane][idx] = 4KB
  int kt = blockIdx.x, w4 = blockIdx.y, Qi = blockIdx.z;
  int t = threadIdx.x;
  int row = t >> 3;                 // 0..31
  int c0 = (t & 7) * 8;             // 0..56
  const float* src = bias + (size_t)(Qi * 128 + w4 * 32 + row) * 2048 + kt * 64 + c0;
  float4 v0 = *(const float4*)(src + 0);
  float4 v1 = *(const float4*)(src + 4);
  float vv[8] = {v0.x, v0.y, v0.z, v0.w, v1.x, v1.y, v1.z, v1.w};
#pragma unroll
  for (int j = 0; j < 8; j++) {
    int kc64 = c0 + j;
    int s = kc64 >> 5, kc5 = kc64 & 31;
    int hi = (kc5 >> 2) & 1, a = kc5 & 3, bq = kc5 >> 3;
    int half = bq >> 1, idx = a + 4 * (bq & 1);
    lb[s][half][hi * 32 + row][idx] = f2bf(vv[j]);
  }
  __syncthreads();
  short8v val = ((const short8v*)&lb[0][0][0][0])[t];
  size_t base = ((size_t)((Qi * 4 + w4) * 32 + kt)) * 2048;  // shorts
  *(short8v*)&frag[base + t * 8] = val;
}

// 4 weight matrices [1024][1024] f32 (row=k,col=n) -> bf16 [n][k], one launch.
__global__ __launch_bounds__(256) void cvt_transpose4(const float* __restrict__ W0,
                                                      const float* __restrict__ W1,
                                                      const float* __restrict__ W2,
                                                      const float* __restrict__ W3,
                                                      short* __restrict__ T0,
                                                      short* __restrict__ T1,
                                                      short* __restrict__ T2,
                                                      short* __restrict__ T3) {
  __shared__ short t_s[64][72];
  int z = blockIdx.z;
  const float* W = (z == 0) ? W0 : (z == 1) ? W1 : (z == 2) ? W2 : W3;
  short* Wt = (z == 0) ? T0 : (z == 1) ? T1 : (z == 2) ? T2 : T3;
  int k0 = blockIdx.y * 64, n0 = blockIdx.x * 64;
  int tid = threadIdx.x;
#pragma unroll
  for (int i = 0; i < 4; i++) {
    int idx = i * 256 + tid;
    int r = idx >> 4, cg = idx & 15;
    float4 v = *(const float4*)&W[(k0 + r) * 1024 + n0 + cg * 4];
    t_s[cg * 4 + 0][r] = f2bf(v.x);
    t_s[cg * 4 + 1][r] = f2bf(v.y);
    t_s[cg * 4 + 2][r] = f2bf(v.z);
    t_s[cg * 4 + 3][r] = f2bf(v.w);
  }
  __syncthreads();
#pragma unroll
  for (int i = 0; i < 2; i++) {
    int idx = i * 256 + tid;
    int r = idx >> 3, cg = idx & 7;
    short8v val = *(short8v*)&t_s[r][cg * 8];
    *(short8v*)&Wt[(n0 + r) * 1024 + k0 + cg * 8] = val;
  }
}

// ---------------- merged Q+KV projection GEMM, 128x128 tiles (m97 structure) ----
// grid 768 (XCD-swizzled, 3 blocks/CU): wk<256 -> Q tile (A=x, Bt=wq, N=1024);
// wk>=256 -> KV tile (A=c, Bt=wkv [2048][1024], N=2048; col<1024 K else V^T).
// 128x128 tile doubles FLOP per LDS-byte vs 64x64 (32.8 vs 16.4 F/B).
__global__ __launch_bounds__(256, 3) void gemm_qkv(const short* __restrict__ x_bf,
                                                   const short* __restrict__ c_bf,
                                                   const short* __restrict__ wq_t,
                                                   const short* __restrict__ wkv_t,
                                                   short* __restrict__ q_ws,
                                                   short* __restrict__ k_ws,
                                                   short* __restrict__ v_ws) {
  __shared__ short a_s[128][64];
  __shared__ short b_s[128][64];
  int tid = threadIdx.x, w = tid >> 6, lane = tid & 63;
  int g = lane >> 4, c16 = lane & 15, hsw = c16 & 7;

  int lin = blockIdx.x;                      // 768 blocks
  int wk = (lin & 7) * 96 + (lin >> 3);      // XCD swizzle (768 = 8*96)
  bool isQ = wk < 256;
  int t0 = isQ ? wk : wk - 256;
  int nt = isQ ? 8 : 16;                     // N-tiles of 128
  int c0 = (t0 % nt) * 128, r0 = (t0 / nt) * 128;
  const short* A  = isQ ? x_bf : c_bf;
  const short* Bt = isQ ? wq_t : wkv_t;

  int wr = (w >> 1) * 64, wc = (w & 1) * 64;
  f32x4 acc[4][4] = {};

  for (int kt = 0; kt < 16; ++kt) {
    int k0 = kt * 64;
    __syncthreads();  // prev compute done before overwrite
#pragma unroll
    for (int i = 0; i < 4; i++) {
      int cb = i * 256 + w * 64;   // wave-uniform chunk base (0..1023)
      int c = cb + lane;
      int row = c >> 3, kg = c & 7;
      int sw = (kg ^ (row & 7)) * 8;   // pre-swizzled source col
      gload16(A + (size_t)(r0 + row) * 1024 + k0 + sw, (char*)a_s + cb * 16);
      gload16(Bt + (size_t)(c0 + row) * 1024 + k0 + sw, (char*)b_s + cb * 16);
    }
    __syncthreads();  // staged tiles visible
#pragma unroll
    for (int kk = 0; kk < 2; kk++) {
      bf16x8 af[4], bf[4];
      int sl0 = ((4 * kk + g) ^ hsw) * 8;
#pragma unroll
      for (int m = 0; m < 4; m++) af[m] = *(const bf16x8*)&a_s[wr + m * 16 + c16][sl0];
#pragma unroll
      for (int n = 0; n < 4; n++) bf[n] = *(const bf16x8*)&b_s[wc + n * 16 + c16][sl0];
#pragma unroll
      for (int m = 0; m < 4; m++)
#pragma unroll
        for (int n = 0; n < 4; n++) acc[m][n] = mfma16(af[m], bf[n], acc[m][n]);
    }
  }

#pragma unroll
  for (int m = 0; m < 4; m++)
#pragma unroll
    for (int n = 0; n < 4; n++)
#pragma unroll
      for (int r = 0; r < 4; r++) {
        int row = r0 + wr + m * 16 + g * 4 + r;  // C/D: row=(lane>>4)*4+reg
        int col = c0 + wc + n * 16 + c16;        //      col=lane&15
        short bv = f2bf(acc[m][n][r]);
        int b = row >> 11, t = row & 2047;
        if (isQ) {
          int h = col >> 6, d = col & 63;
          q_ws[(((b * 16 + h) * 2048) + t) * 64 + d] = bv;
        } else if (col < 1024) {
          int h = col >> 6, d = col & 63;
          k_ws[(((b * 16 + h) * 2048) + t) * 64 + d] = bv;
        } else {
          int cv = col - 1024;
          int h = cv >> 6, d = cv & 63;
          v_ws[(((b * 16 + h) * 64) + d) * 2048 + t] = bv;
        }
      }
}

// ---------------- out GEMM: 64x64 tiles (1024 blocks, 4/CU) ----------------
__global__ __launch_bounds__(256, 4) void gemm_out(const short* __restrict__ A,
                                                   const short* __restrict__ Bt,
                                                   float* __restrict__ out,
                                                   const float* __restrict__ bout) {
  constexpr int KD = 1024;
  __shared__ short a_s[64][64];
  __shared__ short b_s[64][64];
  int tid = threadIdx.x, w = tid >> 6, lane = tid & 63;
  int g = lane >> 4, c16 = lane & 15;
  int hsw = c16 & 7;

  int lin = blockIdx.x + 16 * blockIdx.y;
  int wk = (lin & 7) * 128 + (lin >> 3);
  int c0 = (wk & 15) * 64, r0 = (wk >> 4) * 64;

  int wr = (w >> 1) * 32, wc = (w & 1) * 32;
  f32x4 acc[2][2] = {};

  for (int kt = 0; kt < KD / 64; ++kt) {
    int k0 = kt * 64;
    __syncthreads();
#pragma unroll
    for (int i = 0; i < 2; i++) {
      int cb = i * 256 + w * 64;
      int c = cb + lane;
      int row = c >> 3, kg = c & 7;
      int sw = (kg ^ (row & 7)) * 8;
      gload16(A + (r0 + row) * KD + k0 + sw, (char*)a_s + cb * 16);
      gload16(Bt + (c0 + row) * KD + k0 + sw, (char*)b_s + cb * 16);
    }
    __syncthreads();
#pragma unroll
    for (int kk = 0; kk < 2; kk++) {
      bf16x8 af[2], bf[2];
      int sl0 = ((4 * kk + g) ^ hsw) * 8;
#pragma unroll
      for (int m = 0; m < 2; m++) af[m] = *(const bf16x8*)&a_s[wr + m * 16 + c16][sl0];
#pragma unroll
      for (int n = 0; n < 2; n++) bf[n] = *(const bf16x8*)&b_s[wc + n * 16 + c16][sl0];
#pragma unroll
      for (int m = 0; m < 2; m++)
#pragma unroll
        for (int n = 0; n < 2; n++) acc[m][n] = mfma16(af[m], bf[n], acc[m][n]);
    }
  }

#pragma unroll
  for (int m = 0; m < 2; m++)
#pragma unroll
    for (int n = 0; n < 2; n++)
#pragma unroll
      for (int r = 0; r < 4; r++) {
        int row = r0 + wr + m * 16 + g * 4 + r;
        int col = c0 + wc + n * 16 + c16;
        out[row * 1024 + col] = acc[m][n][r] + bout[col];
      }
}

// ---------------- flash attention v10 ----------------
// = v9 k-split structure, softmax/PV order pipelined within the round:
// QK0 -> SM0 -> [fence] -> QK1 -> PV0 -> SM1 -> PV1, so QK1's dependent-mfma
// latency hides under PV0's work instead of stalling SM1 directly.
__global__ __launch_bounds__(512, 4) void flash_attn(const short* __restrict__ Qg,
                                                     const short* __restrict__ Kg,
                                                     const short* __restrict__ Vtg,
                                                     const short* __restrict__ bfrag,
                                                     short* __restrict__ Og) {
  __shared__ short k_s[2][2][64][64];  // [buf][tile-parity][k][d], swizzled
  __shared__ short v_s[2][2][64][64];  // [buf][tile-parity][d][k], swizzled

  int tid = threadIdx.x, w = tid >> 6, lane = tid & 63;
  int gid = w >> 2, w4 = w & 3;
  int hi = lane >> 5, ll = lane & 31, l7 = ll & 7;

  // head-grouped XCD swizzle: XCD hosts 4 heads x all qb -> K/V L2-fit
  int lin = blockIdx.x + 16 * (blockIdx.y + 16 * blockIdx.z);  // grid (16,16,2)
  int wk = (lin & 7) * 64 + (lin >> 3);
  int Qi = wk & 15;
  int qb = Qi * 128;
  int h = (wk >> 4) & 15;
  int b = wk >> 8;

  const short* Qh = Qg + (size_t)(b * 16 + h) * 2048 * 64;
  const short* Kh = Kg + (size_t)(b * 16 + h) * 2048 * 64;
  const short* Vh = Vtg + (size_t)(b * 16 + h) * 64 * 2048;

  const float C1 = 0.125f * 1.44269504f;                 // atten_scale * log2(e)
  const float C2 = exp2f(-(float)(h + 1)) * 1.44269504f; // head_scale * log2(e)

  int qrow = qb + w4 * 32 + ll;
  const short* bw = bfrag + ((size_t)(Qi * 4 + w4) * 32) * 2048 + lane * 8;

  int srow = tid >> 3, st8 = tid & 7;
  int ssw = (st8 ^ (srow & 7)) * 8;

  // ---- prologue ----
  {
    gload16(Kh + srow * 64 + ssw, (char*)&k_s[0][0][0][0] + w * 64 * 16);
    gload16(Vh + srow * 2048 + ssw, (char*)&v_s[0][0][0][0] + w * 64 * 16);
    gload16(Kh + 64 * 64 + srow * 64 + ssw, (char*)&k_s[0][1][0][0] + w * 64 * 16);
    gload16(Vh + srow * 2048 + 64 + ssw, (char*)&v_s[0][1][0][0] + w * 64 * 16);
  }
  bf16x8 bvA[4];
#pragma unroll
  for (int j = 0; j < 4; j++)
    bvA[j] = *(const bf16x8*)(bw + (size_t)gid * 2048 + j * 512);
  bf16x8 qf[4];
#pragma unroll
  for (int dm = 0; dm < 4; dm++)
    qf[dm] = *(const bf16x8*)(Qh + (size_t)qrow * 64 + dm * 16 + hi * 8);
  asm volatile("" ::: "memory");  // pin prologue VMEM issue order

  float l0 = 0.f, l1 = 0.f, l2 = 0.f, l3 = 0.f;
  f32x16 o_acc[2] = {};

  for (int r = 0; r < 16; ++r) {
    int cur = r & 1;
    int kt = 2 * r + gid;

    bf16x8 bvB[4];
    if (r < 15) {
#pragma unroll
      for (int j = 0; j < 4; j++)
        bvB[j] = *(const bf16x8*)(bw + (size_t)(kt + 2) * 2048 + j * 512);
      int tA = 2 * r + 2;
      gload16(Kh + (size_t)tA * 4096 + srow * 64 + ssw,
              (char*)&k_s[cur ^ 1][0][0][0] + w * 64 * 16);
      gload16(Vh + srow * 2048 + tA * 64 + ssw,
              (char*)&v_s[cur ^ 1][0][0][0] + w * 64 * 16);
      gload16(Kh + (size_t)(tA + 1) * 4096 + srow * 64 + ssw,
              (char*)&k_s[cur ^ 1][1][0][0] + w * 64 * 16);
      gload16(Vh + srow * 2048 + (tA + 1) * 64 + ssw,
              (char*)&v_s[cur ^ 1][1][0][0] + w * 64 * 16);
      asm volatile("s_waitcnt vmcnt(8)" ::: "memory");
    } else {
      asm volatile("s_waitcnt vmcnt(0)" ::: "memory");
    }
    __builtin_amdgcn_s_barrier();  // (a) cur buffer staged on all waves

    // ---- QK subtile 0 ----
    f32x16 sacc = {};
#pragma unroll
    for (int dm = 0; dm < 4; dm++) {
      const short* kr = &k_s[cur][gid][ll][((2 * dm + hi) ^ l7) * 8];
      sacc = mfma32(*(const bf16x8*)kr, qf[dm], sacc);
    }

    // ---- SM0 -> pk0 ----
    unsigned pk0[8];
#pragma unroll
    for (int i = 0; i < 8; i++) {
      float b0 = (float)(i < 4 ? bvA[0][2 * i] : bvA[1][2 * i - 8]);
      float b1 = (float)(i < 4 ? bvA[0][2 * i + 1] : bvA[1][2 * i - 7]);
      float p0 = exp2_native(sacc[2 * i] * C1 + b0 * C2);
      float p1 = exp2_native(sacc[2 * i + 1] * C1 + b1 * C2);
      l0 += p0; l1 += p1;
      bf16x2 pp = {(__bf16)p0, (__bf16)p1};
      pk0[i] = __builtin_bit_cast(unsigned, pp);
    }
    asm volatile("" ::: "memory");  // QK1's ds_reads stay below SM0 (pressure)

    // ---- QK subtile 1 (latency hides under PV0) ----
    f32x16 sacc1 = {};
#pragma unroll
    for (int dm = 0; dm < 4; dm++) {
      const short* kr = &k_s[cur][gid][32 + ll][((2 * dm + hi) ^ l7) * 8];
      sacc1 = mfma32(*(const bf16x8*)kr, qf[dm], sacc1);
    }
    asm volatile("" ::: "memory");  // PV0's ds_reads stay below QK1's

    // ---- PV0 ----
#pragma unroll
    for (int a = 0; a < 2; a++) {
      bf16x8 PA = p_exchange(pk0, a, hi);
#pragma unroll
      for (int dt = 0; dt < 2; dt++) {
        const short* vr = &v_s[cur][gid][dt * 32 + ll][((2 * a + hi) ^ l7) * 8];
        o_acc[dt] = mfma32(PA, *(const bf16x8*)vr, o_acc[dt]);
      }
    }

    // ---- SM1 -> pk1 ----
    unsigned pk1[8];
#pragma unroll
    for (int i = 0; i < 8; i++) {
      float b0 = (float)(i < 4 ? bvA[2][2 * i] : bvA[3][2 * i - 8]);
      float b1 = (float)(i < 4 ? bvA[2][2 * i + 1] : bvA[3][2 * i - 7]);
      float p0 = exp2_native(sacc1[2 * i] * C1 + b0 * C2);
      float p1 = exp2_native(sacc1[2 * i + 1] * C1 + b1 * C2);
      l2 += p0; l3 += p1;
      bf16x2 pp = {(__bf16)p0, (__bf16)p1};
      pk1[i] = __builtin_bit_cast(unsigned, pp);
    }

    // ---- PV1 ----
#pragma unroll
    for (int a = 0; a < 2; a++) {
      bf16x8 PA = p_exchange(pk1, a, hi);
#pragma unroll
      for (int dt = 0; dt < 2; dt++) {
        const short* vr = &v_s[cur][gid][dt * 32 + ll][((4 + 2 * a + hi) ^ l7) * 8];
        o_acc[dt] = mfma32(PA, *(const bf16x8*)vr, o_acc[dt]);
      }
    }
    __builtin_amdgcn_s_barrier();  // (b) all waves done reading cur

#pragma unroll
    for (int j = 0; j < 4; j++) bvA[j] = bvB[j];
  }

  float l_run = (l0 + l1) + (l2 + l3);

  // ---- merge the two k-groups: O = (O_e + O_o)/(l_e + l_o) ----
  l_run += __shfl_xor(l_run, 32);
  float* ox = (float*)&k_s[0][0][0][0];  // [4][32][64] f32 = 32 KB (k_s dead)
  float* lx = (float*)&v_s[0][0][0][0];  // [4][32] f32
  if (gid == 1) {
#pragma unroll
    for (int k = 0; k < 32; k++)
      ox[(w4 * 32 + k) * 64 + lane] = o_acc[k >> 4][k & 15];
    if (lane < 32) lx[w4 * 32 + lane] = l_run;
  }
  __syncthreads();
  if (gid == 0) {
    float invl = 1.f / (l_run + lx[w4 * 32 + ll]);
#pragma unroll
    for (int k = 0; k < 32; k++)
      o_acc[k >> 4][k & 15] += ox[(w4 * 32 + k) * 64 + lane];

#pragma unroll
    for (int r = 0; r < 16; r++) {
      int q = (r & 3) + 8 * (r >> 2) + 4 * hi;
      float iv = __shfl(invl, q);
      int tg = qb + w4 * 32 + q;
#pragma unroll
      for (int dt = 0; dt < 2; dt++) {
        Og[(size_t)(b * 2048 + tg) * 1024 + h * 64 + dt * 32 + ll] =
            f2bf(o_acc[dt][r] * iv);
      }
    }
  }
}

// ---------------- launcher ----------------
extern "C" void kernel_launch(void* const* d_in, const int* in_sizes, int n_in,
                              void* d_out, int out_size, void* d_ws, size_t ws_size,
                              hipStream_t stream) {
  const float* x    = (const float*)d_in[0];
  const float* ctx  = (const float*)d_in[1];
  const float* bias = (const float*)d_in[2];
  const float* Wq   = (const float*)d_in[3];
  const float* Wk   = (const float*)d_in[4];
  const float* Wv   = (const float*)d_in[5];
  const float* Wo   = (const float*)d_in[6];
  const float* bo   = (const float*)d_in[7];
  float* out = (float*)d_out;

  char* ws = (char*)d_ws;
  short* x_bf = (short*)(ws + 0);          // 8 MB; reused as bias frag after QKV-GEMM
  short* c_bf = (short*)(ws + 8388608);    // 8 MB
  short* wq_t = (short*)(ws + 16777216);   // 2 MB  [N][K]
  short* wk_t = (short*)(ws + 18874368);   // 2 MB  (contiguous with wv_t = wkv)
  short* wv_t = (short*)(ws + 20971520);   // 2 MB
  short* wo_t = (short*)(ws + 23068672);   // 2 MB
  short* q_ws = (short*)(ws + 25165824);   // 8 MB  [B,H,T1,64]
  short* k_ws = (short*)(ws + 33554432);   // 8 MB  [B,H,T2,64]
  short* v_ws = (short*)(ws + 41943040);   // 8 MB  [B,H,64,T2]
  short* o_ws = (short*)(ws + 50331648);   // 8 MB  [B,T1,1024]
  short* bias_fr = x_bf;                   // x_bf dead after the QKV-GEMM

  cvt_copy<<<1024, 256, 0, stream>>>(x, x_bf, 1048576);
  cvt_copy<<<1024, 256, 0, stream>>>(ctx, c_bf, 1048576);
  dim3 tg(16, 16, 4);
  cvt_transpose4<<<tg, 256, 0, stream>>>(Wq, Wk, Wv, Wo, wq_t, wk_t, wv_t, wo_t);

  // merged Q + K|V projections, 128^2 tiles, 768 blocks (3/CU)
  gemm_qkv<<<768, 256, 0, stream>>>(x_bf, c_bf, wq_t, wk_t, q_ws, k_ws, v_ws);

  // bias f32 -> bf16 fragment order (into x_bf region, free after QKV-GEMM)
  dim3 bg(32, 4, 16);  // (kt, w4, Qi)
  cvt_bias_frag<<<bg, 256, 0, stream>>>(bias, bias_fr);

  dim3 fg(16, 16, 2);
  flash_attn<<<fg, 512, 0, stream>>>(q_ws, k_ws, v_ws, bias_fr, o_ws);

  dim3 go(16, 64);
  gemm_out<<<go, 256, 0, stream>>>(o_ws, wo_t, out, bo);
}